// Round 9
// baseline (439.626 us; speedup 1.0000x reference)
//
#include <hip/hip_runtime.h>
#include <hip/hip_bf16.h>

// AutoInt+MLP fused forward, MI355X gfx950.  Round 24:
//  - attn: 3 SAMPLES PER WAVE (ILP extension of r23's verified win: 232->211us with
//          2 samples, occupancy dropped yet time improved => latency-bound confirmed).
//          Third independent dep chain per wave; weight fragments feed 9 MFMAs each;
//          per-sample S^T->softmax keeps ONE ST tensor live at a time (peak ~210 VGPR).
//          Grid 5462 = ceil(16384/3), tail sample clamped (duplicate compute, benign).
//          Phase order & all layouts identical to r23/r22 verified substrate.
//  - dnn : frozen round-10 optimum.
//  HARD RULES: no 2-arg __launch_bounds__; no merged heterogeneous dispatch;
//  dnn M=64 spills; dnn 512-thr & paired-field regress; attn 2-sample/4-wave
//  block FAILED (r19); hoisted GROUPED short8 weight arrays FAILED (r19+r20,
//  corruption signature) — banned; setprio regresses (r21).

#define NF     39
#define EMB    64
#define NLAYER 3
#define VOCAB  1000
#define FLAT   2496
#define H1     512
#define H2     256
#define NS     3          // samples per attn block/wave

typedef __attribute__((ext_vector_type(8))) short  short8;
typedef __attribute__((ext_vector_type(4))) float  floatx4;

__device__ __forceinline__ short8 ld8s(const unsigned short* p) {
    return *(const short8*)p;
}
__device__ __forceinline__ float b2f(unsigned short h) {
    union { unsigned u; float f; } x; x.u = ((unsigned)h) << 16; return x.f;
}
__device__ __forceinline__ unsigned short f2b(float f) {
    union { float f; unsigned u; } x; x.f = f;
    unsigned u = x.u;
    return (unsigned short)((u + 0x7fffu + ((u >> 16) & 1u)) >> 16);
}
// 2 floats -> packed bf16x2 in ONE VALU op (gfx950 hw cvt, RNE)
__device__ __forceinline__ unsigned cvt_pk(float a, float b) {
#if defined(__gfx950__)
    unsigned r;
    asm("v_cvt_pk_bf16_f32 %0, %1, %2" : "=v"(r) : "v"(a), "v"(b));
    return r;
#else
    return (unsigned)f2b(a) | ((unsigned)f2b(b) << 16);
#endif
}
// 4 packed bf16x2 words -> short8 MFMA operand (register re-arrangement only)
__device__ __forceinline__ short8 pk8(unsigned a, unsigned b, unsigned c, unsigned d) {
    union { unsigned u[4]; short8 s; } x;
    x.u[0] = a; x.u[1] = b; x.u[2] = c; x.u[3] = d;
    return x.s;
}

// ------- prep: attention weights f32 [L][64(k)][64(o)] -> bf16 [L][o][k] --------------
__global__ void attw_t(const float* __restrict__ WQ, const float* __restrict__ WK,
                       const float* __restrict__ WV, const float* __restrict__ WR,
                       unsigned short* __restrict__ wqt, unsigned short* __restrict__ wkt,
                       unsigned short* __restrict__ wvt, unsigned short* __restrict__ wrt)
{
    int idx = blockIdx.x * 256 + threadIdx.x;       // 4*3*4096 = 49152
    if (idx >= 4 * 3 * 4096) return;
    int mat = idx / 12288;
    int rem = idx % 12288;
    int l   = rem / 4096;
    int ok  = rem % 4096;
    int o = ok >> 6, k = ok & 63;
    const float*    src = (mat == 0) ? WQ : (mat == 1) ? WK : (mat == 2) ? WV : WR;
    unsigned short* dst = (mat == 0) ? wqt : (mat == 1) ? wkt : (mat == 2) ? wvt : wrt;
    dst[l * 4096 + o * 64 + k] = f2b(src[l * 4096 + k * 64 + o]);
}

// ------- prep: W1 f32 [2496][512] -> bf16 fragment-linear w1p --------------------------
__global__ void w1pack(const float* __restrict__ W1, unsigned short* __restrict__ w1p)
{
    int t = blockIdx.x * 256 + threadIdx.x;        // 624*256 = 159744 = 2496*64
    int lane = t & 63, grp = t >> 6;               // grp 0..2495
    int ot = grp / 78, kk = grp % 78;
    int q = lane >> 4, n = ot * 16 + (lane & 15);
    int kb = kk * 32 + q * 8;
    unsigned short* dst = w1p + grp * 512 + lane * 8;
    #pragma unroll
    for (int j = 0; j < 8; ++j)
        dst[j] = f2b(W1[(kb + j) * 512 + n]);
}

// ------- prep: W2 f32 [512][256] -> bf16 fragment-linear w2p ---------------------------
__global__ void w2pack(const float* __restrict__ W2, unsigned short* __restrict__ w2p)
{
    int t = blockIdx.x * 256 + threadIdx.x;        // 64*256 = 16384 = 256*64
    int lane = t & 63, grp = t >> 6;               // grp 0..255
    int ot = grp / 16, kk = grp % 16;
    int q = lane >> 4, n = ot * 16 + (lane & 15);
    int kb = kk * 32 + q * 8;
    unsigned short* dst = w2p + grp * 512 + lane * 8;
    #pragma unroll
    for (int j = 0; j < 8; ++j)
        dst[j] = f2b(W2[(kb + j) * 256 + n]);
}

// ------- fused attention: 3 samples/block, 2 waves (wave = head, ALL samples) ---------
// 5462 blocks x 128 thr. LDS: xss 3x6912 + red 24 = 20760 B.
// All of Q/K/V/P live in registers; xss is the only LDS tile (cross-head x).
__global__ void __launch_bounds__(128) attn_kernel(
    const int* __restrict__ X,
    const float* __restrict__ embf,
    const unsigned short* __restrict__ wqt,
    const unsigned short* __restrict__ wkt,
    const unsigned short* __restrict__ wvt,
    const unsigned short* __restrict__ wrt,
    const float* __restrict__ wlinf,
    float* __restrict__ att_out)
{
    __shared__ unsigned short xss[NS][48 * 72];    // per sample: [token 48][col 64+8pad]
    __shared__ float red[NS][2];                   // [sample][wave]

    const int tid  = threadIdx.x;
    const int wid  = tid >> 6;          // 0..1
    const int lane = tid & 63;
    const int h    = wid;               // head
    const int quad = lane >> 4;
    const int l16  = lane & 15;
    const int samp0 = blockIdx.x * NS;

    int sidx[NS];                       // clamped sample ids (tail block duplicates last)
    #pragma unroll
    for (int s = 0; s < NS; ++s) {
        int v = samp0 + s;
        sidx[s] = v < 16384 ? v : 16383;
    }

    // ---- embedding gather: wave fills its head's cols for ALL samples -----------------
    {
        const int tq = lane >> 4;            // 0..3
        const int cp = (lane & 15) * 2;      // 0,2,..,30
        const int col = h * 32 + cp;
        #pragma unroll
        for (int s = 0; s < NS; ++s) {
            const int* xrow = X + sidx[s] * NF;
            #pragma unroll
            for (int t0 = 0; t0 < 48; t0 += 4) {
                int t = t0 + tq;
                unsigned pk = 0;
                if (t < NF) {
                    int row = xrow[t] + t * VOCAB;
                    const float2 v = *(const float2*)&embf[row * EMB + col];
                    pk = cvt_pk(v.x, v.y);
                }
                *(unsigned*)&xss[s][t * 72 + col] = pk;   // rows 39..47 zeroed
            }
        }
    }
    __syncthreads();

    // ---- hoisted per-lane constants ---------------------------------------------------
    const int wro = (h * 32 + l16) * 64 + quad * 8;    // +ot*1024 per 16-row tile
    const unsigned short* wqp = wqt + wro;
    const unsigned short* wkp = wkt + wro;
    const unsigned short* wvq = wvt + wro;
    const unsigned short* wrp = wrt + wro;
    float m2[4];                                       // jt=2 softmax mask (j=32+quad*4+r)
    #pragma unroll
    for (int r = 0; r < 4; ++r)
        m2[r] = (32 + quad * 4 + r < NF) ? 1.f : 0.f;

    for (int layer = 0; layer < NLAYER; ++layer) {
        // ---- xss fragments for all samples (only LDS reads this layer) ----------------
        short8 xf[NS][3][2];
        #pragma unroll
        for (int s = 0; s < NS; ++s)
            #pragma unroll
            for (int tt = 0; tt < 3; ++tt)
                #pragma unroll
                for (int kk = 0; kk < 2; ++kk)
                    xf[s][tt][kk] = ld8s(&xss[s][(tt * 16 + l16) * 72 + kk * 32 + quad * 8]);

        __syncthreads();   // both waves consumed xss -> writeback at end is race-free

        // ---- Q,K projections, weights SHARED across samples ---------------------------
        unsigned qw[NS][2][3][2], kw[NS][2][3][2];   // [s][ot][tt][word]
        #pragma unroll
        for (int mat = 0; mat < 2; ++mat) {
            const unsigned short* wt = mat ? wkp : wqp;
            #pragma unroll
            for (int ot = 0; ot < 2; ++ot) {
                short8 w0 = ld8s(wt + ot * 1024);
                short8 w1 = ld8s(wt + ot * 1024 + 32);
                #pragma unroll
                for (int s = 0; s < NS; ++s)
                    #pragma unroll
                    for (int tt = 0; tt < 3; ++tt) {
                        floatx4 c = {0.f, 0.f, 0.f, 0.f};
                        c = __builtin_amdgcn_mfma_f32_16x16x32_bf16(w0, xf[s][tt][0], c, 0, 0, 0);
                        c = __builtin_amdgcn_mfma_f32_16x16x32_bf16(w1, xf[s][tt][1], c, 0, 0, 0);
                        if (mat == 0) {
                            qw[s][ot][tt][0] = cvt_pk(c[0], c[1]);
                            qw[s][ot][tt][1] = cvt_pk(c[2], c[3]);
                        } else {
                            kw[s][ot][tt][0] = cvt_pk(c[0], c[1]);
                            kw[s][ot][tt][1] = cvt_pk(c[2], c[3]);
                        }
                    }
            }
        }

        // ---- R projection -> O init (weights shared) ----------------------------------
        floatx4 O[NS][2][3];                         // [s][dt][it]
        #pragma unroll
        for (int dt = 0; dt < 2; ++dt) {
            short8 w0 = ld8s(wrp + dt * 1024);
            short8 w1 = ld8s(wrp + dt * 1024 + 32);
            #pragma unroll
            for (int s = 0; s < NS; ++s)
                #pragma unroll
                for (int it = 0; it < 3; ++it) {
                    floatx4 c = {0.f, 0.f, 0.f, 0.f};
                    c = __builtin_amdgcn_mfma_f32_16x16x32_bf16(w0, xf[s][it][0], c, 0, 0, 0);
                    c = __builtin_amdgcn_mfma_f32_16x16x32_bf16(w1, xf[s][it][1], c, 0, 0, 0);
                    O[s][dt][it] = c;
                }
        }

        // ---- V projection -> vw (weights shared; xf dies here) ------------------------
        unsigned vw[NS][3][2][2];                    // [s][mt][nt][word]
        #pragma unroll
        for (int nt = 0; nt < 2; ++nt) {
            short8 w0 = ld8s(wvq + nt * 1024);
            short8 w1 = ld8s(wvq + nt * 1024 + 32);
            #pragma unroll
            for (int s = 0; s < NS; ++s)
                #pragma unroll
                for (int mt = 0; mt < 3; ++mt) {
                    floatx4 c = {0.f, 0.f, 0.f, 0.f};
                    c = __builtin_amdgcn_mfma_f32_16x16x32_bf16(xf[s][mt][0], w0, c, 0, 0, 0);
                    c = __builtin_amdgcn_mfma_f32_16x16x32_bf16(xf[s][mt][1], w1, c, 0, 0, 0);
                    vw[s][mt][nt][0] = cvt_pk(c[0], c[1]);
                    vw[s][mt][nt][1] = cvt_pk(c[2], c[3]);
                }
        }

        // ---- per sample: S^T then softmax (ONE ST tensor live at a time) --------------
        unsigned pw[NS][3][3][2];                    // [s][jt][it][word]
        #pragma unroll
        for (int s = 0; s < NS; ++s) {
            floatx4 ST[3][3];
            #pragma unroll
            for (int jt = 0; jt < 3; ++jt) {
                short8 a = pk8(kw[s][0][jt][0], kw[s][0][jt][1], kw[s][1][jt][0], kw[s][1][jt][1]);
                #pragma unroll
                for (int it = 0; it < 3; ++it) {
                    short8 b = pk8(qw[s][0][it][0], qw[s][0][it][1], qw[s][1][it][0], qw[s][1][it][1]);
                    floatx4 z = {0.f, 0.f, 0.f, 0.f};
                    ST[jt][it] = __builtin_amdgcn_mfma_f32_16x16x32_bf16(a, b, z, 0, 0, 0);
                }
            }
            #pragma unroll
            for (int it = 0; it < 3; ++it) {
                float p[3][4];
                float sum = 0.f;
                #pragma unroll
                for (int jt = 0; jt < 3; ++jt)
                    #pragma unroll
                    for (int r = 0; r < 4; ++r) {
                        float e = __expf(ST[jt][it][r]);
                        if (jt == 2) e *= m2[r];
                        p[jt][r] = e;
                        sum += e;
                    }
                sum += __shfl_xor(sum, 16, 64);
                sum += __shfl_xor(sum, 32, 64);
                float inv = 1.0f / sum;
                #pragma unroll
                for (int jt = 0; jt < 3; ++jt) {
                    pw[s][jt][it][0] = cvt_pk(p[jt][0] * inv, p[jt][1] * inv);
                    pw[s][jt][it][1] = cvt_pk(p[jt][2] * inv, p[jt][3] * inv);
                }
            }
        }

        // ---- O^T += V^T @ P^T per sample ----------------------------------------------
        #pragma unroll
        for (int s = 0; s < NS; ++s)
            #pragma unroll
            for (int dt = 0; dt < 2; ++dt) {
                short8 a01 = pk8(vw[s][0][dt][0], vw[s][0][dt][1], vw[s][1][dt][0], vw[s][1][dt][1]);
                short8 a2  = pk8(vw[s][2][dt][0], vw[s][2][dt][1], 0u, 0u);
                #pragma unroll
                for (int it = 0; it < 3; ++it) {
                    short8 b01 = pk8(pw[s][0][it][0], pw[s][0][it][1], pw[s][1][it][0], pw[s][1][it][1]);
                    short8 b2  = pk8(pw[s][2][it][0], pw[s][2][it][1], 0u, 0u);
                    O[s][dt][it] = __builtin_amdgcn_mfma_f32_16x16x32_bf16(a01, b01, O[s][dt][it], 0, 0, 0);
                    O[s][dt][it] = __builtin_amdgcn_mfma_f32_16x16x32_bf16(a2,  b2,  O[s][dt][it], 0, 0, 0);
                }
            }

        // ---- next x = relu(O^T): write xss[s][tok][d] ---------------------------------
        #pragma unroll
        for (int s = 0; s < NS; ++s)
            #pragma unroll
            for (int dt = 0; dt < 2; ++dt)
                #pragma unroll
                for (int it = 0; it < 3; ++it) {
                    uint2 w;
                    w.x = cvt_pk(fmaxf(O[s][dt][it][0], 0.f), fmaxf(O[s][dt][it][1], 0.f));
                    w.y = cvt_pk(fmaxf(O[s][dt][it][2], 0.f), fmaxf(O[s][dt][it][3], 0.f));
                    *(uint2*)&xss[s][(it * 16 + l16) * 72 + h * 32 + dt * 16 + quad * 4] = w;
                }

        __syncthreads();   // xss rewritten before next layer's xf loads

        wqp += 4096; wkp += 4096; wvq += 4096; wrp += 4096;   // next layer's weights
    }

    // ---- att logit: relu( att_flat . Wlin ), all samples ------------------------------
    {
        const int c = lane & 31, tp = lane >> 5;
        const int col = h * 32 + c;
        #pragma unroll
        for (int s = 0; s < NS; ++s) {
            float acc = 0.f;
            for (int t0 = 0; t0 < 40; t0 += 2) {
                int t = t0 + tp;
                if (t < NF)
                    acc += b2f(xss[s][t * 72 + col]) * wlinf[t * EMB + col];
            }
            #pragma unroll
            for (int off = 1; off < 64; off <<= 1)
                acc += __shfl_xor(acc, off, 64);
            if (lane == 0) red[s][wid] = acc;
        }
        __syncthreads();
        if (tid == 0) {
            #pragma unroll
            for (int s = 0; s < NS; ++s)
                att_out[sidx[s]] = fmaxf(red[s][0] + red[s][1], 0.f);
        }
    }
}

// ------- DNN (ROUND-10 VERBATIM, frozen optimum): 32-sample tile, packed B-loads ------
// 512 blocks x 256 thr. LDS: ea 9216 + h1s 33280 = 42496 B.
__global__ void __launch_bounds__(256) dnn_kernel(
    const int* __restrict__ X,
    const float* __restrict__ embf,
    const unsigned short* __restrict__ w1p,
    const float* __restrict__ b1v,
    const unsigned short* __restrict__ w2p,
    const float* __restrict__ b2v,
    const float* __restrict__ w3v,
    const float* __restrict__ b3v,
    const float* __restrict__ att_in,
    float* __restrict__ out)
{
    __shared__ unsigned short ea[2][32 * 72];     // double-buffered [sample 32][64+8pad]
    __shared__ unsigned short h1s[32 * 520];      // h1 [32][512+8pad]; h2 [32][264] aliases
    unsigned short* h2s = h1s;

    const int tid  = threadIdx.x;
    const int wid  = tid >> 6, lane = tid & 63, quad = lane >> 4, l16 = lane & 15;
    const int S0   = blockIdx.x * 32;

    floatx4 C1[2][8];
    #pragma unroll
    for (int mt = 0; mt < 2; ++mt)
        #pragma unroll
        for (int nt = 0; nt < 8; ++nt)
            C1[mt][nt] = (floatx4){0.f, 0.f, 0.f, 0.f};

    const int gs = tid >> 3;        // 0..31 sample for staging
    const int gg = tid & 7;         // 8 floats each

    // prologue: stage field 0 into ea[0]
    {
        int row = X[(S0 + gs) * NF + 0];
        const float4* src = (const float4*)&embf[row * EMB + gg * 8];
        float4 v0 = src[0], v1 = src[1];
        uint4 u;
        u.x = cvt_pk(v0.x, v0.y); u.y = cvt_pk(v0.z, v0.w);
        u.z = cvt_pk(v1.x, v1.y); u.w = cvt_pk(v1.z, v1.w);
        *(uint4*)&ea[0][gs * 72 + gg * 8] = u;
    }
    __syncthreads();

    // ---- phase 1: h1 = emb(32 x 2496) @ W1, K streamed per field, dbuf, 1 sync/iter ---
    for (int f = 0; f < NF; ++f) {
        if (f < NF - 1) {   // stage next field into the other buffer (disjoint from reads)
            int row = X[(S0 + gs) * NF + f + 1] + (f + 1) * VOCAB;
            const float4* src = (const float4*)&embf[row * EMB + gg * 8];
            float4 v0 = src[0], v1 = src[1];
            uint4 u;
            u.x = cvt_pk(v0.x, v0.y); u.y = cvt_pk(v0.z, v0.w);
            u.z = cvt_pk(v1.x, v1.y); u.w = cvt_pk(v1.z, v1.w);
            *(uint4*)&ea[(f + 1) & 1][gs * 72 + gg * 8] = u;
        }
        const unsigned short* eac = ea[f & 1];
        short8 a[2][2];
        #pragma unroll
        for (int mt = 0; mt < 2; ++mt) {
            a[mt][0] = ld8s(&eac[(mt * 16 + l16) * 72 + quad * 8]);
            a[mt][1] = ld8s(&eac[(mt * 16 + l16) * 72 + 32 + quad * 8]);
        }
        #pragma unroll
        for (int nt = 0; nt < 8; ++nt) {
            const unsigned short* bp = w1p + (((wid * 8 + nt) * 78 + f * 2) * 64 + lane) * 8;
            short8 b0 = ld8s(bp);
            short8 b1 = ld8s(bp + 512);
            #pragma unroll
            for (int mt = 0; mt < 2; ++mt) {
                C1[mt][nt] = __builtin_amdgcn_mfma_f32_16x16x32_bf16(a[mt][0], b0, C1[mt][nt], 0, 0, 0);
                C1[mt][nt] = __builtin_amdgcn_mfma_f32_16x16x32_bf16(a[mt][1], b1, C1[mt][nt], 0, 0, 0);
            }
        }
        __syncthreads();   // waves may not drift >1 iter: protects both ea buffers
    }

    // bias + relu, write ALL of h1 to LDS (each wave owns 128 cols)
    #pragma unroll
    for (int nt = 0; nt < 8; ++nt) {
        float bb = b1v[wid * 128 + nt * 16 + l16];
        #pragma unroll
        for (int mt = 0; mt < 2; ++mt) {
            #pragma unroll
            for (int r = 0; r < 4; ++r) {
                float v = fmaxf(C1[mt][nt][r] + bb, 0.f);
                h1s[(mt * 16 + quad * 4 + r) * 520 + wid * 128 + nt * 16 + l16] = f2b(v);
            }
        }
    }
    __syncthreads();

    // ---- phase 2: h2 = h1(32 x 512) @ W2, single pass, wave owns 64 N-cols ------------
    floatx4 C2[2][4];
    #pragma unroll
    for (int mt = 0; mt < 2; ++mt)
        #pragma unroll
        for (int nt = 0; nt < 4; ++nt)
            C2[mt][nt] = (floatx4){0.f, 0.f, 0.f, 0.f};

    #pragma unroll 4
    for (int kk = 0; kk < 16; ++kk) {
        short8 a0 = ld8s(&h1s[(l16) * 520 + kk * 32 + quad * 8]);
        short8 a1 = ld8s(&h1s[(16 + l16) * 520 + kk * 32 + quad * 8]);
        #pragma unroll
        for (int nt = 0; nt < 4; ++nt) {
            short8 b = ld8s(w2p + (((wid * 4 + nt) * 16 + kk) * 64 + lane) * 8);
            C2[0][nt] = __builtin_amdgcn_mfma_f32_16x16x32_bf16(a0, b, C2[0][nt], 0, 0, 0);
            C2[1][nt] = __builtin_amdgcn_mfma_f32_16x16x32_bf16(a1, b, C2[1][nt], 0, 0, 0);
        }
    }
    __syncthreads();    // h1 reads complete -> safe to alias h2s onto h1s

    #pragma unroll
    for (int nt = 0; nt < 4; ++nt) {
        float bb = b2v[wid * 64 + nt * 16 + l16];
        #pragma unroll
        for (int mt = 0; mt < 2; ++mt)
            #pragma unroll
            for (int r = 0; r < 4; ++r)
                h2s[(mt * 16 + quad * 4 + r) * 264 + wid * 64 + nt * 16 + l16] =
                    f2b(fmaxf(C2[mt][nt][r] + bb, 0.f));
    }
    __syncthreads();

    // ---- phase 3: dnn = relu(h2 . W3 + b3); out = sigmoid(att + dnn), f32 -------------
    {
        int s = tid >> 3, part = tid & 7;     // 8 lanes per sample, 32 elems each
        float acc = 0.f;
        #pragma unroll 8
        for (int j = 0; j < 32; ++j) {
            int jj = part * 32 + j;
            acc += b2f(h2s[s * 264 + jj]) * w3v[jj];
        }
        acc += __shfl_xor(acc, 1, 64);
        acc += __shfl_xor(acc, 2, 64);
        acc += __shfl_xor(acc, 4, 64);
        if (part == 0) {
            float dnn = fmaxf(acc + b3v[0], 0.f);
            float v = dnn + att_in[S0 + s];
            out[S0 + s] = 1.f / (1.f + __expf(-v));
        }
    }
}

extern "C" void kernel_launch(void* const* d_in, const int* in_sizes, int n_in,
                              void* d_out, int out_size, void* d_ws, size_t ws_size,
                              hipStream_t stream)
{
    (void)in_sizes; (void)n_in; (void)out_size; (void)ws_size;

    const int*   X    = (const int*)d_in[0];
    const float* emb  = (const float*)d_in[1];
    const float* WQ   = (const float*)d_in[2];
    const float* WK   = (const float*)d_in[3];
    const float* WV   = (const float*)d_in[4];
    const float* WR   = (const float*)d_in[5];
    const float* W1   = (const float*)d_in[6];
    const float* b1   = (const float*)d_in[7];
    const float* W2   = (const float*)d_in[8];
    const float* b2   = (const float*)d_in[9];
    const float* W3   = (const float*)d_in[10];
    const float* b3   = (const float*)d_in[11];
    const float* Wlin = (const float*)d_in[12];

    char* ws = (char*)d_ws;
    float*          att_logit = (float*)ws;                          // 16384 f32 = 64KB
    unsigned short* wqt = (unsigned short*)(ws + 65536);             // 3*4096 shorts each
    unsigned short* wkt = wqt + 3 * 4096;
    unsigned short* wvt = wkt + 3 * 4096;
    unsigned short* wrt = wvt + 3 * 4096;
    unsigned short* w1p = wrt + 3 * 4096;                            // 2496*512 shorts
    unsigned short* w2p = w1p + 2496 * 512;                          // 256*512 shorts

    attw_t<<<192, 256, 0, stream>>>(WQ, WK, WV, WR, wqt, wkt, wvt, wrt);
    w1pack<<<624, 256, 0, stream>>>(W1, w1p);
    w2pack<<<64, 256, 0, stream>>>(W2, w2p);
    attn_kernel<<<(16384 + NS - 1) / NS, 128, 0, stream>>>(X, emb, wqt, wkt, wvt, wrt,
                                                           Wlin, att_logit);
    dnn_kernel<<<512, 256, 0, stream>>>(X, emb, w1p, b1, w2p, b2, W3, b3, att_logit,
                                        (float*)d_out);
}

// Round 10
// 404.176 us; speedup vs baseline: 1.0877x; 1.0877x over previous
//
#include <hip/hip_runtime.h>
#include <hip/hip_bf16.h>

// AutoInt+MLP fused forward, MI355X gfx950.  Round 25:
//  - attn: BARRIER-FREE / LDS-FREE rewrite. wave = one whole sample (both heads).
//          Diagnosis r18-r24: latency-bound; barriers (cross-head LDS exchange) are
//          the last structural coupling. Fix: one wave computes BOTH heads, so the
//          layer output C-frag feeds the next layer's projections directly from
//          registers via the verified concat-slot trick. Weights are pre-packed with
//          the matching K-slot permutation k=(e>>2)*16+quad*4+(e&3) (attw_t).
//          Embedding gathered straight into that slot layout; final Wlin dot from
//          registers. ZERO __syncthreads, ZERO __shared__. Total MFMA count
//          unchanged; all MFMA layouts are the r22/r23-verified ones.
//          NS=3 regressed (VGPR 160, occ 11%) -> single sample/wave here.
//          No short8 arrays (r19/r20 ban): weights stay immediate-use w0/w1;
//          persistent state is u32/f32 arrays with static (unrolled) indexing.
//  - dnn : frozen round-10 optimum.
//  HARD RULES: no 2-arg __launch_bounds__; no merged heterogeneous dispatch;
//  dnn M=64 spills; dnn 512-thr & paired-field regress; attn 2-sample/4-wave
//  block FAILED (r19); hoisted GROUPED short8 weight arrays FAILED (r19+r20,
//  corruption signature) — banned; setprio regresses (r21); NS=3 regresses (r24).

#define NF     39
#define EMB    64
#define NLAYER 3
#define VOCAB  1000
#define FLAT   2496
#define H1     512
#define H2     256

typedef __attribute__((ext_vector_type(8))) short  short8;
typedef __attribute__((ext_vector_type(4))) float  floatx4;

__device__ __forceinline__ short8 ld8s(const unsigned short* p) {
    return *(const short8*)p;
}
__device__ __forceinline__ float b2f(unsigned short h) {
    union { unsigned u; float f; } x; x.u = ((unsigned)h) << 16; return x.f;
}
__device__ __forceinline__ float b2f_lo(unsigned w) { return b2f((unsigned short)(w & 0xffffu)); }
__device__ __forceinline__ float b2f_hi(unsigned w) { return b2f((unsigned short)(w >> 16)); }
__device__ __forceinline__ unsigned short f2b(float f) {
    union { float f; unsigned u; } x; x.f = f;
    unsigned u = x.u;
    return (unsigned short)((u + 0x7fffu + ((u >> 16) & 1u)) >> 16);
}
// 2 floats -> packed bf16x2 in ONE VALU op (gfx950 hw cvt, RNE); a -> low half
__device__ __forceinline__ unsigned cvt_pk(float a, float b) {
#if defined(__gfx950__)
    unsigned r;
    asm("v_cvt_pk_bf16_f32 %0, %1, %2" : "=v"(r) : "v"(a), "v"(b));
    return r;
#else
    return (unsigned)f2b(a) | ((unsigned)f2b(b) << 16);
#endif
}
// 4 packed bf16x2 words -> short8 MFMA operand (register re-arrangement only)
__device__ __forceinline__ short8 pk8(unsigned a, unsigned b, unsigned c, unsigned d) {
    union { unsigned u[4]; short8 s; } x;
    x.u[0] = a; x.u[1] = b; x.u[2] = c; x.u[3] = d;
    return x.s;
}

// ------- prep: attention weights f32 [L][64 k][64 o] -> bf16 [L][o][pos] --------------
// pos = kk*32 + quad*8 + e  holds  k = kk*32 + (e>>2)*16 + quad*4 + (e&3)
// (K-slot permutation so the C-frag concat trick feeds projections register-direct)
__global__ void attw_t(const float* __restrict__ WQ, const float* __restrict__ WK,
                       const float* __restrict__ WV, const float* __restrict__ WR,
                       unsigned short* __restrict__ wqt, unsigned short* __restrict__ wkt,
                       unsigned short* __restrict__ wvt, unsigned short* __restrict__ wrt)
{
    int idx = blockIdx.x * 256 + threadIdx.x;       // 4*3*4096 = 49152
    if (idx >= 4 * 3 * 4096) return;
    int mat = idx / 12288;
    int rem = idx % 12288;
    int l   = rem / 4096;
    int ok  = rem % 4096;
    int o = ok >> 6, pos = ok & 63;
    int kk = pos >> 5, q = (pos >> 3) & 3, e = pos & 7;
    int k = kk * 32 + (e >> 2) * 16 + q * 4 + (e & 3);
    const float*    src = (mat == 0) ? WQ : (mat == 1) ? WK : (mat == 2) ? WV : WR;
    unsigned short* dst = (mat == 0) ? wqt : (mat == 1) ? wkt : (mat == 2) ? wvt : wrt;
    dst[l * 4096 + o * 64 + pos] = f2b(src[l * 4096 + k * 64 + o]);
}

// ------- prep: W1 f32 [2496][512] -> bf16 fragment-linear w1p --------------------------
__global__ void w1pack(const float* __restrict__ W1, unsigned short* __restrict__ w1p)
{
    int t = blockIdx.x * 256 + threadIdx.x;        // 624*256 = 159744 = 2496*64
    int lane = t & 63, grp = t >> 6;               // grp 0..2495
    int ot = grp / 78, kk = grp % 78;
    int q = lane >> 4, n = ot * 16 + (lane & 15);
    int kb = kk * 32 + q * 8;
    unsigned short* dst = w1p + grp * 512 + lane * 8;
    #pragma unroll
    for (int j = 0; j < 8; ++j)
        dst[j] = f2b(W1[(kb + j) * 512 + n]);
}

// ------- prep: W2 f32 [512][256] -> bf16 fragment-linear w2p ---------------------------
__global__ void w2pack(const float* __restrict__ W2, unsigned short* __restrict__ w2p)
{
    int t = blockIdx.x * 256 + threadIdx.x;        // 64*256 = 16384 = 256*64
    int lane = t & 63, grp = t >> 6;               // grp 0..255
    int ot = grp / 16, kk = grp % 16;
    int q = lane >> 4, n = ot * 16 + (lane & 15);
    int kb = kk * 32 + q * 8;
    unsigned short* dst = w2p + grp * 512 + lane * 8;
    #pragma unroll
    for (int j = 0; j < 8; ++j)
        dst[j] = f2b(W2[(kb + j) * 256 + n]);
}

// ------- fused attention: 1 sample/WAVE, 4 samples/block, NO LDS, NO barriers ---------
// 4096 blocks x 256 thr. Whole layer chain lives in registers.
// x operand slot map (both A and B sides): slot (quad,e) -> dim (e>>2)*16+quad*4+(e&3)
// per kk*32 half — identical to the C-frag concat mapping, so O feeds next layer.
__global__ void __launch_bounds__(256) attn_kernel(
    const int* __restrict__ X,
    const float* __restrict__ embf,
    const unsigned short* __restrict__ wqt,
    const unsigned short* __restrict__ wkt,
    const unsigned short* __restrict__ wvt,
    const unsigned short* __restrict__ wrt,
    const float* __restrict__ wlinf,
    float* __restrict__ att_out)
{
    const int tid  = threadIdx.x;
    const int wid  = tid >> 6;          // 0..3 -> sample slot
    const int lane = tid & 63;
    const int quad = lane >> 4;
    const int l16  = lane & 15;
    const int samp = blockIdx.x * 4 + wid;

    // ---- x fragments in registers: xiw[tt][kk][word], word w: dims per slot map ------
    unsigned xiw[3][2][4];
    {
        const int* xrow = X + samp * NF;
        #pragma unroll
        for (int tt = 0; tt < 3; ++tt) {
            const int tok = tt * 16 + l16;
            if (tok < NF) {
                const int row = xrow[tok] + tok * VOCAB;
                const float* er = embf + row * EMB;
                #pragma unroll
                for (int kk = 0; kk < 2; ++kk) {
                    const float4 lo = *(const float4*)(er + kk * 32 + quad * 4);
                    const float4 hi = *(const float4*)(er + kk * 32 + 16 + quad * 4);
                    xiw[tt][kk][0] = cvt_pk(lo.x, lo.y);
                    xiw[tt][kk][1] = cvt_pk(lo.z, lo.w);
                    xiw[tt][kk][2] = cvt_pk(hi.x, hi.y);
                    xiw[tt][kk][3] = cvt_pk(hi.z, hi.w);
                }
            } else {
                #pragma unroll
                for (int kk = 0; kk < 2; ++kk)
                    #pragma unroll
                    for (int w = 0; w < 4; ++w)
                        xiw[tt][kk][w] = 0u;
            }
        }
    }

    // ---- hoisted per-lane constants ---------------------------------------------------
    const int wro_l = l16 * 64 + quad * 8;      // per-lane base within one [o][64] tile
    const unsigned short* wq = wqt + wro_l;
    const unsigned short* wk = wkt + wro_l;
    const unsigned short* wv = wvt + wro_l;
    const unsigned short* wr = wrt + wro_l;
    float m2[4];                                // jt=2 softmax mask (j=32+quad*4+r)
    #pragma unroll
    for (int r = 0; r < 4; ++r)
        m2[r] = (32 + quad * 4 + r < NF) ? 1.f : 0.f;

    #define XF(tt,kk) pk8(xiw[tt][kk][0], xiw[tt][kk][1], xiw[tt][kk][2], xiw[tt][kk][3])

    for (int layer = 0; layer < NLAYER; ++layer) {
        // ---- per head: Q,K proj -> S^T -> softmax -> pw[h] ----------------------------
        unsigned pw[2][3][3][2];                // [h][jt][it][word]
        #pragma unroll
        for (int h = 0; h < 2; ++h) {
            unsigned qw[2][3][2], kw[2][3][2];  // [ot local][tt][word]
            #pragma unroll
            for (int mat = 0; mat < 2; ++mat) {
                const unsigned short* wt = (mat ? wk : wq) + h * 2048;
                #pragma unroll
                for (int ot = 0; ot < 2; ++ot) {
                    short8 w0 = ld8s(wt + ot * 1024);
                    short8 w1 = ld8s(wt + ot * 1024 + 32);
                    #pragma unroll
                    for (int tt = 0; tt < 3; ++tt) {
                        floatx4 c = {0.f, 0.f, 0.f, 0.f};
                        c = __builtin_amdgcn_mfma_f32_16x16x32_bf16(w0, XF(tt,0), c, 0, 0, 0);
                        c = __builtin_amdgcn_mfma_f32_16x16x32_bf16(w1, XF(tt,1), c, 0, 0, 0);
                        if (mat == 0) {
                            qw[ot][tt][0] = cvt_pk(c[0], c[1]);
                            qw[ot][tt][1] = cvt_pk(c[2], c[3]);
                        } else {
                            kw[ot][tt][0] = cvt_pk(c[0], c[1]);
                            kw[ot][tt][1] = cvt_pk(c[2], c[3]);
                        }
                    }
                }
            }
            // S^T = K @ Q^T, K=32 concat over the head's two 16-o blocks
            floatx4 ST[3][3];
            #pragma unroll
            for (int jt = 0; jt < 3; ++jt) {
                short8 a = pk8(kw[0][jt][0], kw[0][jt][1], kw[1][jt][0], kw[1][jt][1]);
                #pragma unroll
                for (int it = 0; it < 3; ++it) {
                    short8 b = pk8(qw[0][it][0], qw[0][it][1], qw[1][it][0], qw[1][it][1]);
                    floatx4 z = {0.f, 0.f, 0.f, 0.f};
                    ST[jt][it] = __builtin_amdgcn_mfma_f32_16x16x32_bf16(a, b, z, 0, 0, 0);
                }
            }
            // softmax over j (within-lane + shfl_xor 16,32)
            #pragma unroll
            for (int it = 0; it < 3; ++it) {
                float p[3][4];
                float sum = 0.f;
                #pragma unroll
                for (int jt = 0; jt < 3; ++jt)
                    #pragma unroll
                    for (int r = 0; r < 4; ++r) {
                        float e = __expf(ST[jt][it][r]);
                        if (jt == 2) e *= m2[r];
                        p[jt][r] = e;
                        sum += e;
                    }
                sum += __shfl_xor(sum, 16, 64);
                sum += __shfl_xor(sum, 32, 64);
                float inv = 1.0f / sum;
                #pragma unroll
                for (int jt = 0; jt < 3; ++jt) {
                    pw[h][jt][it][0] = cvt_pk(p[jt][0] * inv, p[jt][1] * inv);
                    pw[h][jt][it][1] = cvt_pk(p[jt][2] * inv, p[jt][3] * inv);
                }
            }
        }

        // ---- V projection -> vw over all 4 d-blocks -----------------------------------
        unsigned vw[3][4][2];                   // [mt tok-tile][nt d-block][word]
        #pragma unroll
        for (int nt = 0; nt < 4; ++nt) {
            short8 w0 = ld8s(wv + nt * 1024);
            short8 w1 = ld8s(wv + nt * 1024 + 32);
            #pragma unroll
            for (int mt = 0; mt < 3; ++mt) {
                floatx4 c = {0.f, 0.f, 0.f, 0.f};
                c = __builtin_amdgcn_mfma_f32_16x16x32_bf16(XF(mt,0), w0, c, 0, 0, 0);
                c = __builtin_amdgcn_mfma_f32_16x16x32_bf16(XF(mt,1), w1, c, 0, 0, 0);
                vw[mt][nt][0] = cvt_pk(c[0], c[1]);
                vw[mt][nt][1] = cvt_pk(c[2], c[3]);
            }
        }

        // ---- R projection -> O init over all 4 d-blocks -------------------------------
        floatx4 O[4][3];                        // [dt][it]
        #pragma unroll
        for (int dt = 0; dt < 4; ++dt) {
            short8 w0 = ld8s(wr + dt * 1024);
            short8 w1 = ld8s(wr + dt * 1024 + 32);
            #pragma unroll
            for (int it = 0; it < 3; ++it) {
                floatx4 c = {0.f, 0.f, 0.f, 0.f};
                c = __builtin_amdgcn_mfma_f32_16x16x32_bf16(w0, XF(it,0), c, 0, 0, 0);
                c = __builtin_amdgcn_mfma_f32_16x16x32_bf16(w1, XF(it,1), c, 0, 0, 0);
                O[dt][it] = c;
            }
        }

        // ---- O += V^T @ P^T per head (dt = 2h+dtl) ------------------------------------
        #pragma unroll
        for (int h = 0; h < 2; ++h)
            #pragma unroll
            for (int dtl = 0; dtl < 2; ++dtl) {
                const int dt = h * 2 + dtl;
                short8 a01 = pk8(vw[0][dt][0], vw[0][dt][1], vw[1][dt][0], vw[1][dt][1]);
                short8 a2  = pk8(vw[2][dt][0], vw[2][dt][1], 0u, 0u);
                #pragma unroll
                for (int it = 0; it < 3; ++it) {
                    short8 b01 = pk8(pw[h][0][it][0], pw[h][0][it][1], pw[h][1][it][0], pw[h][1][it][1]);
                    short8 b2  = pk8(pw[h][2][it][0], pw[h][2][it][1], 0u, 0u);
                    O[dt][it] = __builtin_amdgcn_mfma_f32_16x16x32_bf16(a01, b01, O[dt][it], 0, 0, 0);
                    O[dt][it] = __builtin_amdgcn_mfma_f32_16x16x32_bf16(a2,  b2,  O[dt][it], 0, 0, 0);
                }
            }

        // ---- next x = relu(O) packed straight back into xiw (slot map preserved) ------
        #pragma unroll
        for (int it = 0; it < 3; ++it)
            #pragma unroll
            for (int kk = 0; kk < 2; ++kk) {
                const int d0 = kk * 2, d1 = kk * 2 + 1;
                xiw[it][kk][0] = cvt_pk(fmaxf(O[d0][it][0], 0.f), fmaxf(O[d0][it][1], 0.f));
                xiw[it][kk][1] = cvt_pk(fmaxf(O[d0][it][2], 0.f), fmaxf(O[d0][it][3], 0.f));
                xiw[it][kk][2] = cvt_pk(fmaxf(O[d1][it][0], 0.f), fmaxf(O[d1][it][1], 0.f));
                xiw[it][kk][3] = cvt_pk(fmaxf(O[d1][it][2], 0.f), fmaxf(O[d1][it][3], 0.f));
            }

        wq += 4096; wk += 4096; wv += 4096; wr += 4096;   // next layer's weights
    }

    // ---- att logit: relu( att_flat . Wlin ) from registers, full-wave reduce ----------
    {
        float acc = 0.f;
        #pragma unroll
        for (int tt = 0; tt < 3; ++tt) {
            const int tok = tt * 16 + l16;
            if (tok < NF) {
                const float* wl = wlinf + tok * EMB;
                #pragma unroll
                for (int kk = 0; kk < 2; ++kk) {
                    const float4 A = *(const float4*)(wl + kk * 32 + quad * 4);
                    const float4 B = *(const float4*)(wl + kk * 32 + 16 + quad * 4);
                    acc += b2f_lo(xiw[tt][kk][0]) * A.x + b2f_hi(xiw[tt][kk][0]) * A.y;
                    acc += b2f_lo(xiw[tt][kk][1]) * A.z + b2f_hi(xiw[tt][kk][1]) * A.w;
                    acc += b2f_lo(xiw[tt][kk][2]) * B.x + b2f_hi(xiw[tt][kk][2]) * B.y;
                    acc += b2f_lo(xiw[tt][kk][3]) * B.z + b2f_hi(xiw[tt][kk][3]) * B.w;
                }
            }
        }
        #pragma unroll
        for (int off = 1; off < 64; off <<= 1)
            acc += __shfl_xor(acc, off, 64);
        if (lane == 0)
            att_out[samp] = fmaxf(acc, 0.f);
    }
    #undef XF
}

// ------- DNN (ROUND-10 VERBATIM, frozen optimum): 32-sample tile, packed B-loads ------
// 512 blocks x 256 thr. LDS: ea 9216 + h1s 33280 = 42496 B.
__global__ void __launch_bounds__(256) dnn_kernel(
    const int* __restrict__ X,
    const float* __restrict__ embf,
    const unsigned short* __restrict__ w1p,
    const float* __restrict__ b1v,
    const unsigned short* __restrict__ w2p,
    const float* __restrict__ b2v,
    const float* __restrict__ w3v,
    const float* __restrict__ b3v,
    const float* __restrict__ att_in,
    float* __restrict__ out)
{
    __shared__ unsigned short ea[2][32 * 72];     // double-buffered [sample 32][64+8pad]
    __shared__ unsigned short h1s[32 * 520];      // h1 [32][512+8pad]; h2 [32][264] aliases
    unsigned short* h2s = h1s;

    const int tid  = threadIdx.x;
    const int wid  = tid >> 6, lane = tid & 63, quad = lane >> 4, l16 = lane & 15;
    const int S0   = blockIdx.x * 32;

    floatx4 C1[2][8];
    #pragma unroll
    for (int mt = 0; mt < 2; ++mt)
        #pragma unroll
        for (int nt = 0; nt < 8; ++nt)
            C1[mt][nt] = (floatx4){0.f, 0.f, 0.f, 0.f};

    const int gs = tid >> 3;        // 0..31 sample for staging
    const int gg = tid & 7;         // 8 floats each

    // prologue: stage field 0 into ea[0]
    {
        int row = X[(S0 + gs) * NF + 0];
        const float4* src = (const float4*)&embf[row * EMB + gg * 8];
        float4 v0 = src[0], v1 = src[1];
        uint4 u;
        u.x = cvt_pk(v0.x, v0.y); u.y = cvt_pk(v0.z, v0.w);
        u.z = cvt_pk(v1.x, v1.y); u.w = cvt_pk(v1.z, v1.w);
        *(uint4*)&ea[0][gs * 72 + gg * 8] = u;
    }
    __syncthreads();

    // ---- phase 1: h1 = emb(32 x 2496) @ W1, K streamed per field, dbuf, 1 sync/iter ---
    for (int f = 0; f < NF; ++f) {
        if (f < NF - 1) {   // stage next field into the other buffer (disjoint from reads)
            int row = X[(S0 + gs) * NF + f + 1] + (f + 1) * VOCAB;
            const float4* src = (const float4*)&embf[row * EMB + gg * 8];
            float4 v0 = src[0], v1 = src[1];
            uint4 u;
            u.x = cvt_pk(v0.x, v0.y); u.y = cvt_pk(v0.z, v0.w);
            u.z = cvt_pk(v1.x, v1.y); u.w = cvt_pk(v1.z, v1.w);
            *(uint4*)&ea[(f + 1) & 1][gs * 72 + gg * 8] = u;
        }
        const unsigned short* eac = ea[f & 1];
        short8 a[2][2];
        #pragma unroll
        for (int mt = 0; mt < 2; ++mt) {
            a[mt][0] = ld8s(&eac[(mt * 16 + l16) * 72 + quad * 8]);
            a[mt][1] = ld8s(&eac[(mt * 16 + l16) * 72 + 32 + quad * 8]);
        }
        #pragma unroll
        for (int nt = 0; nt < 8; ++nt) {
            const unsigned short* bp = w1p + (((wid * 8 + nt) * 78 + f * 2) * 64 + lane) * 8;
            short8 b0 = ld8s(bp);
            short8 b1 = ld8s(bp + 512);
            #pragma unroll
            for (int mt = 0; mt < 2; ++mt) {
                C1[mt][nt] = __builtin_amdgcn_mfma_f32_16x16x32_bf16(a[mt][0], b0, C1[mt][nt], 0, 0, 0);
                C1[mt][nt] = __builtin_amdgcn_mfma_f32_16x16x32_bf16(a[mt][1], b1, C1[mt][nt], 0, 0, 0);
            }
        }
        __syncthreads();   // waves may not drift >1 iter: protects both ea buffers
    }

    // bias + relu, write ALL of h1 to LDS (each wave owns 128 cols)
    #pragma unroll
    for (int nt = 0; nt < 8; ++nt) {
        float bb = b1v[wid * 128 + nt * 16 + l16];
        #pragma unroll
        for (int mt = 0; mt < 2; ++mt) {
            #pragma unroll
            for (int r = 0; r < 4; ++r) {
                float v = fmaxf(C1[mt][nt][r] + bb, 0.f);
                h1s[(mt * 16 + quad * 4 + r) * 520 + wid * 128 + nt * 16 + l16] = f2b(v);
            }
        }
    }
    __syncthreads();

    // ---- phase 2: h2 = h1(32 x 512) @ W2, single pass, wave owns 64 N-cols ------------
    floatx4 C2[2][4];
    #pragma unroll
    for (int mt = 0; mt < 2; ++mt)
        #pragma unroll
        for (int nt = 0; nt < 4; ++nt)
            C2[mt][nt] = (floatx4){0.f, 0.f, 0.f, 0.f};

    #pragma unroll 4
    for (int kk = 0; kk < 16; ++kk) {
        short8 a0 = ld8s(&h1s[(l16) * 520 + kk * 32 + quad * 8]);
        short8 a1 = ld8s(&h1s[(16 + l16) * 520 + kk * 32 + quad * 8]);
        #pragma unroll
        for (int nt = 0; nt < 4; ++nt) {
            short8 b = ld8s(w2p + (((wid * 4 + nt) * 16 + kk) * 64 + lane) * 8);
            C2[0][nt] = __builtin_amdgcn_mfma_f32_16x16x32_bf16(a0, b, C2[0][nt], 0, 0, 0);
            C2[1][nt] = __builtin_amdgcn_mfma_f32_16x16x32_bf16(a1, b, C2[1][nt], 0, 0, 0);
        }
    }
    __syncthreads();    // h1 reads complete -> safe to alias h2s onto h1s

    #pragma unroll
    for (int nt = 0; nt < 4; ++nt) {
        float bb = b2v[wid * 64 + nt * 16 + l16];
        #pragma unroll
        for (int mt = 0; mt < 2; ++mt)
            #pragma unroll
            for (int r = 0; r < 4; ++r)
                h2s[(mt * 16 + quad * 4 + r) * 264 + wid * 64 + nt * 16 + l16] =
                    f2b(fmaxf(C2[mt][nt][r] + bb, 0.f));
    }
    __syncthreads();

    // ---- phase 3: dnn = relu(h2 . W3 + b3); out = sigmoid(att + dnn), f32 -------------
    {
        int s = tid >> 3, part = tid & 7;     // 8 lanes per sample, 32 elems each
        float acc = 0.f;
        #pragma unroll 8
        for (int j = 0; j < 32; ++j) {
            int jj = part * 32 + j;
            acc += b2f(h2s[s * 264 + jj]) * w3v[jj];
        }
        acc += __shfl_xor(acc, 1, 64);
        acc += __shfl_xor(acc, 2, 64);
        acc += __shfl_xor(acc, 4, 64);
        if (part == 0) {
            float dnn = fmaxf(acc + b3v[0], 0.f);
            float v = dnn + att_in[S0 + s];
            out[S0 + s] = 1.f / (1.f + __expf(-v));
        }
    }
}

extern "C" void kernel_launch(void* const* d_in, const int* in_sizes, int n_in,
                              void* d_out, int out_size, void* d_ws, size_t ws_size,
                              hipStream_t stream)
{
    (void)in_sizes; (void)n_in; (void)out_size; (void)ws_size;

    const int*   X    = (const int*)d_in[0];
    const float* emb  = (const float*)d_in[1];
    const float* WQ   = (const float*)d_in[2];
    const float* WK   = (const float*)d_in[3];
    const float* WV   = (const float*)d_in[4];
    const float* WR   = (const float*)d_in[5];
    const float* W1   = (const float*)d_in[6];
    const float* b1   = (const float*)d_in[7];
    const float* W2   = (const float*)d_in[8];
    const float* b2   = (const float*)d_in[9];
    const float* W3   = (const float*)d_in[10];
    const float* b3   = (const float*)d_in[11];
    const float* Wlin = (const float*)d_in[12];

    char* ws = (char*)d_ws;
    float*          att_logit = (float*)ws;                          // 16384 f32 = 64KB
    unsigned short* wqt = (unsigned short*)(ws + 65536);             // 3*4096 shorts each
    unsigned short* wkt = wqt + 3 * 4096;
    unsigned short* wvt = wkt + 3 * 4096;
    unsigned short* wrt = wvt + 3 * 4096;
    unsigned short* w1p = wrt + 3 * 4096;                            // 2496*512 shorts
    unsigned short* w2p = w1p + 2496 * 512;                          // 256*512 shorts

    attw_t<<<192, 256, 0, stream>>>(WQ, WK, WV, WR, wqt, wkt, wvt, wrt);
    w1pack<<<624, 256, 0, stream>>>(W1, w1p);
    w2pack<<<64, 256, 0, stream>>>(W2, w2p);
    attn_kernel<<<4096, 256, 0, stream>>>(X, emb, wqt, wkt, wvt, wrt, Wlin, att_logit);
    dnn_kernel<<<512, 256, 0, stream>>>(X, emb, w1p, b1, w2p, b2, W3, b3, att_logit,
                                        (float*)d_out);
}

// Round 11
// 402.087 us; speedup vs baseline: 1.0934x; 1.0052x over previous
//
#include <hip/hip_runtime.h>
#include <hip/hip_bf16.h>

// AutoInt+MLP fused forward, MI355X gfx950.  Round 26:
//  - attn: barrier-free/LDS-free (r25 structure) + PHASE-MAJOR HEAD INTERLEAVE
//          (r23 discipline). r25 regression root-cause: CDNA waves issue IN-ORDER,
//          so per-wave ILP only pays if the COMPILE-TIME schedule interleaves
//          independent chains; r25's per-head monolithic phases serialized them.
//          This round: every phase loops h innermost -> adjacent independent MFMA/
//          VALU pairs (exactly how r23 won 234->211), with zero barriers/LDS kept.
//          All datapath pieces are r25-verified (slot-permuted weights, register-
//          resident x, concat-slot S^T/PV); only instruction ORDER changes.
//          Weight loads stay immediate-use named scalars (no short8 arrays).
//  - dnn : frozen round-10 optimum.
//  HARD RULES: no 2-arg __launch_bounds__; no merged heterogeneous dispatch;
//  dnn M=64 spills; dnn 512-thr & paired-field regress; attn 2-sample/4-wave
//  block FAILED (r19); hoisted GROUPED short8 weight arrays FAILED (r19+r20) —
//  banned; setprio regresses (r21); NS=3 regresses (r24); per-head monolithic
//  phase order regresses (r25).

#define NF     39
#define EMB    64
#define NLAYER 3
#define VOCAB  1000
#define FLAT   2496
#define H1     512
#define H2     256

typedef __attribute__((ext_vector_type(8))) short  short8;
typedef __attribute__((ext_vector_type(4))) float  floatx4;

__device__ __forceinline__ short8 ld8s(const unsigned short* p) {
    return *(const short8*)p;
}
__device__ __forceinline__ float b2f(unsigned short h) {
    union { unsigned u; float f; } x; x.u = ((unsigned)h) << 16; return x.f;
}
__device__ __forceinline__ float b2f_lo(unsigned w) { return b2f((unsigned short)(w & 0xffffu)); }
__device__ __forceinline__ float b2f_hi(unsigned w) { return b2f((unsigned short)(w >> 16)); }
__device__ __forceinline__ unsigned short f2b(float f) {
    union { float f; unsigned u; } x; x.f = f;
    unsigned u = x.u;
    return (unsigned short)((u + 0x7fffu + ((u >> 16) & 1u)) >> 16);
}
// 2 floats -> packed bf16x2 in ONE VALU op (gfx950 hw cvt, RNE); a -> low half
__device__ __forceinline__ unsigned cvt_pk(float a, float b) {
#if defined(__gfx950__)
    unsigned r;
    asm("v_cvt_pk_bf16_f32 %0, %1, %2" : "=v"(r) : "v"(a), "v"(b));
    return r;
#else
    return (unsigned)f2b(a) | ((unsigned)f2b(b) << 16);
#endif
}
// 4 packed bf16x2 words -> short8 MFMA operand (register re-arrangement only)
__device__ __forceinline__ short8 pk8(unsigned a, unsigned b, unsigned c, unsigned d) {
    union { unsigned u[4]; short8 s; } x;
    x.u[0] = a; x.u[1] = b; x.u[2] = c; x.u[3] = d;
    return x.s;
}

// ------- prep: attention weights f32 [L][64 k][64 o] -> bf16 [L][o][pos] --------------
// pos = kk*32 + quad*8 + e  holds  k = kk*32 + (e>>2)*16 + quad*4 + (e&3)
// (K-slot permutation so the C-frag concat trick feeds projections register-direct)
__global__ void attw_t(const float* __restrict__ WQ, const float* __restrict__ WK,
                       const float* __restrict__ WV, const float* __restrict__ WR,
                       unsigned short* __restrict__ wqt, unsigned short* __restrict__ wkt,
                       unsigned short* __restrict__ wvt, unsigned short* __restrict__ wrt)
{
    int idx = blockIdx.x * 256 + threadIdx.x;       // 4*3*4096 = 49152
    if (idx >= 4 * 3 * 4096) return;
    int mat = idx / 12288;
    int rem = idx % 12288;
    int l   = rem / 4096;
    int ok  = rem % 4096;
    int o = ok >> 6, pos = ok & 63;
    int kk = pos >> 5, q = (pos >> 3) & 3, e = pos & 7;
    int k = kk * 32 + (e >> 2) * 16 + q * 4 + (e & 3);
    const float*    src = (mat == 0) ? WQ : (mat == 1) ? WK : (mat == 2) ? WV : WR;
    unsigned short* dst = (mat == 0) ? wqt : (mat == 1) ? wkt : (mat == 2) ? wvt : wrt;
    dst[l * 4096 + o * 64 + pos] = f2b(src[l * 4096 + k * 64 + o]);
}

// ------- prep: W1 f32 [2496][512] -> bf16 fragment-linear w1p --------------------------
__global__ void w1pack(const float* __restrict__ W1, unsigned short* __restrict__ w1p)
{
    int t = blockIdx.x * 256 + threadIdx.x;        // 624*256 = 159744 = 2496*64
    int lane = t & 63, grp = t >> 6;               // grp 0..2495
    int ot = grp / 78, kk = grp % 78;
    int q = lane >> 4, n = ot * 16 + (lane & 15);
    int kb = kk * 32 + q * 8;
    unsigned short* dst = w1p + grp * 512 + lane * 8;
    #pragma unroll
    for (int j = 0; j < 8; ++j)
        dst[j] = f2b(W1[(kb + j) * 512 + n]);
}

// ------- prep: W2 f32 [512][256] -> bf16 fragment-linear w2p ---------------------------
__global__ void w2pack(const float* __restrict__ W2, unsigned short* __restrict__ w2p)
{
    int t = blockIdx.x * 256 + threadIdx.x;        // 64*256 = 16384 = 256*64
    int lane = t & 63, grp = t >> 6;               // grp 0..255
    int ot = grp / 16, kk = grp % 16;
    int q = lane >> 4, n = ot * 16 + (lane & 15);
    int kb = kk * 32 + q * 8;
    unsigned short* dst = w2p + grp * 512 + lane * 8;
    #pragma unroll
    for (int j = 0; j < 8; ++j)
        dst[j] = f2b(W2[(kb + j) * 256 + n]);
}

// ------- fused attention: 1 sample/WAVE, 4 samples/block, NO LDS, NO barriers ---------
// 4096 blocks x 256 thr. Whole layer chain lives in registers; phases loop h innermost
// so the compiler emits the two heads' chains interleaved (in-order issue needs this).
__global__ void __launch_bounds__(256) attn_kernel(
    const int* __restrict__ X,
    const float* __restrict__ embf,
    const unsigned short* __restrict__ wqt,
    const unsigned short* __restrict__ wkt,
    const unsigned short* __restrict__ wvt,
    const unsigned short* __restrict__ wrt,
    const float* __restrict__ wlinf,
    float* __restrict__ att_out)
{
    const int tid  = threadIdx.x;
    const int wid  = tid >> 6;          // 0..3 -> sample slot
    const int lane = tid & 63;
    const int quad = lane >> 4;
    const int l16  = lane & 15;
    const int samp = blockIdx.x * 4 + wid;

    // ---- x fragments in registers: xiw[tt][kk][word], word w: dims per slot map ------
    unsigned xiw[3][2][4];
    {
        const int* xrow = X + samp * NF;
        #pragma unroll
        for (int tt = 0; tt < 3; ++tt) {
            const int tok = tt * 16 + l16;
            if (tok < NF) {
                const int row = xrow[tok] + tok * VOCAB;
                const float* er = embf + row * EMB;
                #pragma unroll
                for (int kk = 0; kk < 2; ++kk) {
                    const float4 lo = *(const float4*)(er + kk * 32 + quad * 4);
                    const float4 hi = *(const float4*)(er + kk * 32 + 16 + quad * 4);
                    xiw[tt][kk][0] = cvt_pk(lo.x, lo.y);
                    xiw[tt][kk][1] = cvt_pk(lo.z, lo.w);
                    xiw[tt][kk][2] = cvt_pk(hi.x, hi.y);
                    xiw[tt][kk][3] = cvt_pk(hi.z, hi.w);
                }
            } else {
                #pragma unroll
                for (int kk = 0; kk < 2; ++kk)
                    #pragma unroll
                    for (int w = 0; w < 4; ++w)
                        xiw[tt][kk][w] = 0u;
            }
        }
    }

    // ---- hoisted per-lane constants ---------------------------------------------------
    const int wro_l = l16 * 64 + quad * 8;      // per-lane base within one [o][64] tile
    const unsigned short* wq = wqt + wro_l;
    const unsigned short* wk = wkt + wro_l;
    const unsigned short* wv = wvt + wro_l;
    const unsigned short* wr = wrt + wro_l;
    float m2[4];                                // jt=2 softmax mask (j=32+quad*4+r)
    #pragma unroll
    for (int r = 0; r < 4; ++r)
        m2[r] = (32 + quad * 4 + r < NF) ? 1.f : 0.f;

    #define XF(tt,kk) pk8(xiw[tt][kk][0], xiw[tt][kk][1], xiw[tt][kk][2], xiw[tt][kk][3])

    for (int layer = 0; layer < NLAYER; ++layer) {
        // ---- Q,K projections: h-interleaved MFMA pairs --------------------------------
        unsigned qw[2][2][3][2], kw[2][2][3][2];   // [h][ot][tt][word]
        #pragma unroll
        for (int mat = 0; mat < 2; ++mat) {
            #pragma unroll
            for (int ot = 0; ot < 2; ++ot) {
                const unsigned short* wt = (mat ? wk : wq) + ot * 1024;
                short8 wa0 = ld8s(wt);              // head 0
                short8 wa1 = ld8s(wt + 32);
                short8 wb0 = ld8s(wt + 2048);       // head 1
                short8 wb1 = ld8s(wt + 2048 + 32);
                #pragma unroll
                for (int tt = 0; tt < 3; ++tt) {
                    floatx4 c0 = {0.f, 0.f, 0.f, 0.f};
                    floatx4 c1 = {0.f, 0.f, 0.f, 0.f};
                    c0 = __builtin_amdgcn_mfma_f32_16x16x32_bf16(wa0, XF(tt,0), c0, 0, 0, 0);
                    c1 = __builtin_amdgcn_mfma_f32_16x16x32_bf16(wb0, XF(tt,0), c1, 0, 0, 0);
                    c0 = __builtin_amdgcn_mfma_f32_16x16x32_bf16(wa1, XF(tt,1), c0, 0, 0, 0);
                    c1 = __builtin_amdgcn_mfma_f32_16x16x32_bf16(wb1, XF(tt,1), c1, 0, 0, 0);
                    if (mat == 0) {
                        qw[0][ot][tt][0] = cvt_pk(c0[0], c0[1]);
                        qw[0][ot][tt][1] = cvt_pk(c0[2], c0[3]);
                        qw[1][ot][tt][0] = cvt_pk(c1[0], c1[1]);
                        qw[1][ot][tt][1] = cvt_pk(c1[2], c1[3]);
                    } else {
                        kw[0][ot][tt][0] = cvt_pk(c0[0], c0[1]);
                        kw[0][ot][tt][1] = cvt_pk(c0[2], c0[3]);
                        kw[1][ot][tt][0] = cvt_pk(c1[0], c1[1]);
                        kw[1][ot][tt][1] = cvt_pk(c1[2], c1[3]);
                    }
                }
            }
        }

        // ---- S^T both heads, h-interleaved --------------------------------------------
        floatx4 ST[2][3][3];                    // [h][jt][it]
        #pragma unroll
        for (int jt = 0; jt < 3; ++jt) {
            short8 a0 = pk8(kw[0][0][jt][0], kw[0][0][jt][1], kw[0][1][jt][0], kw[0][1][jt][1]);
            short8 a1 = pk8(kw[1][0][jt][0], kw[1][0][jt][1], kw[1][1][jt][0], kw[1][1][jt][1]);
            #pragma unroll
            for (int it = 0; it < 3; ++it) {
                short8 b0 = pk8(qw[0][0][it][0], qw[0][0][it][1], qw[0][1][it][0], qw[0][1][it][1]);
                short8 b1 = pk8(qw[1][0][it][0], qw[1][0][it][1], qw[1][1][it][0], qw[1][1][it][1]);
                floatx4 z = {0.f, 0.f, 0.f, 0.f};
                ST[0][jt][it] = __builtin_amdgcn_mfma_f32_16x16x32_bf16(a0, b0, z, 0, 0, 0);
                ST[1][jt][it] = __builtin_amdgcn_mfma_f32_16x16x32_bf16(a1, b1, z, 0, 0, 0);
            }
        }

        // ---- softmax both heads, interleaved at it level ------------------------------
        unsigned pw[2][3][3][2];                // [h][jt][it][word]
        #pragma unroll
        for (int it = 0; it < 3; ++it) {
            #pragma unroll
            for (int h = 0; h < 2; ++h) {
                float p[3][4];
                float sum = 0.f;
                #pragma unroll
                for (int jt = 0; jt < 3; ++jt)
                    #pragma unroll
                    for (int r = 0; r < 4; ++r) {
                        float e = __expf(ST[h][jt][it][r]);
                        if (jt == 2) e *= m2[r];
                        p[jt][r] = e;
                        sum += e;
                    }
                sum += __shfl_xor(sum, 16, 64);
                sum += __shfl_xor(sum, 32, 64);
                float inv = 1.0f / sum;
                #pragma unroll
                for (int jt = 0; jt < 3; ++jt) {
                    pw[h][jt][it][0] = cvt_pk(p[jt][0] * inv, p[jt][1] * inv);
                    pw[h][jt][it][1] = cvt_pk(p[jt][2] * inv, p[jt][3] * inv);
                }
            }
        }

        // ---- V projection -> vw over all 4 d-blocks -----------------------------------
        unsigned vw[3][4][2];                   // [mt tok-tile][nt d-block][word]
        #pragma unroll
        for (int nt = 0; nt < 4; ++nt) {
            short8 w0 = ld8s(wv + nt * 1024);
            short8 w1 = ld8s(wv + nt * 1024 + 32);
            #pragma unroll
            for (int mt = 0; mt < 3; ++mt) {
                floatx4 c = {0.f, 0.f, 0.f, 0.f};
                c = __builtin_amdgcn_mfma_f32_16x16x32_bf16(XF(mt,0), w0, c, 0, 0, 0);
                c = __builtin_amdgcn_mfma_f32_16x16x32_bf16(XF(mt,1), w1, c, 0, 0, 0);
                vw[mt][nt][0] = cvt_pk(c[0], c[1]);
                vw[mt][nt][1] = cvt_pk(c[2], c[3]);
            }
        }

        // ---- R projection -> O init over all 4 d-blocks -------------------------------
        floatx4 O[4][3];                        // [dt][it]
        #pragma unroll
        for (int dt = 0; dt < 4; ++dt) {
            short8 w0 = ld8s(wr + dt * 1024);
            short8 w1 = ld8s(wr + dt * 1024 + 32);
            #pragma unroll
            for (int it = 0; it < 3; ++it) {
                floatx4 c = {0.f, 0.f, 0.f, 0.f};
                c = __builtin_amdgcn_mfma_f32_16x16x32_bf16(w0, XF(it,0), c, 0, 0, 0);
                c = __builtin_amdgcn_mfma_f32_16x16x32_bf16(w1, XF(it,1), c, 0, 0, 0);
                O[dt][it] = c;
            }
        }

        // ---- O += V^T @ P^T, h-interleaved (dt = 2h+dtl) ------------------------------
        #pragma unroll
        for (int dtl = 0; dtl < 2; ++dtl)
            #pragma unroll
            for (int h = 0; h < 2; ++h) {
                const int dt = h * 2 + dtl;
                short8 a01 = pk8(vw[0][dt][0], vw[0][dt][1], vw[1][dt][0], vw[1][dt][1]);
                short8 a2  = pk8(vw[2][dt][0], vw[2][dt][1], 0u, 0u);
                #pragma unroll
                for (int it = 0; it < 3; ++it) {
                    short8 b01 = pk8(pw[h][0][it][0], pw[h][0][it][1], pw[h][1][it][0], pw[h][1][it][1]);
                    short8 b2  = pk8(pw[h][2][it][0], pw[h][2][it][1], 0u, 0u);
                    O[dt][it] = __builtin_amdgcn_mfma_f32_16x16x32_bf16(a01, b01, O[dt][it], 0, 0, 0);
                    O[dt][it] = __builtin_amdgcn_mfma_f32_16x16x32_bf16(a2,  b2,  O[dt][it], 0, 0, 0);
                }
            }

        // ---- next x = relu(O) packed straight back into xiw (slot map preserved) ------
        #pragma unroll
        for (int it = 0; it < 3; ++it)
            #pragma unroll
            for (int kk = 0; kk < 2; ++kk) {
                const int d0 = kk * 2, d1 = kk * 2 + 1;
                xiw[it][kk][0] = cvt_pk(fmaxf(O[d0][it][0], 0.f), fmaxf(O[d0][it][1], 0.f));
                xiw[it][kk][1] = cvt_pk(fmaxf(O[d0][it][2], 0.f), fmaxf(O[d0][it][3], 0.f));
                xiw[it][kk][2] = cvt_pk(fmaxf(O[d1][it][0], 0.f), fmaxf(O[d1][it][1], 0.f));
                xiw[it][kk][3] = cvt_pk(fmaxf(O[d1][it][2], 0.f), fmaxf(O[d1][it][3], 0.f));
            }

        wq += 4096; wk += 4096; wv += 4096; wr += 4096;   // next layer's weights
    }

    // ---- att logit: relu( att_flat . Wlin ) from registers, full-wave reduce ----------
    {
        float acc = 0.f;
        #pragma unroll
        for (int tt = 0; tt < 3; ++tt) {
            const int tok = tt * 16 + l16;
            if (tok < NF) {
                const float* wl = wlinf + tok * EMB;
                #pragma unroll
                for (int kk = 0; kk < 2; ++kk) {
                    const float4 A = *(const float4*)(wl + kk * 32 + quad * 4);
                    const float4 B = *(const float4*)(wl + kk * 32 + 16 + quad * 4);
                    acc += b2f_lo(xiw[tt][kk][0]) * A.x + b2f_hi(xiw[tt][kk][0]) * A.y;
                    acc += b2f_lo(xiw[tt][kk][1]) * A.z + b2f_hi(xiw[tt][kk][1]) * A.w;
                    acc += b2f_lo(xiw[tt][kk][2]) * B.x + b2f_hi(xiw[tt][kk][2]) * B.y;
                    acc += b2f_lo(xiw[tt][kk][3]) * B.z + b2f_hi(xiw[tt][kk][3]) * B.w;
                }
            }
        }
        #pragma unroll
        for (int off = 1; off < 64; off <<= 1)
            acc += __shfl_xor(acc, off, 64);
        if (lane == 0)
            att_out[samp] = fmaxf(acc, 0.f);
    }
    #undef XF
}

// ------- DNN (ROUND-10 VERBATIM, frozen optimum): 32-sample tile, packed B-loads ------
// 512 blocks x 256 thr. LDS: ea 9216 + h1s 33280 = 42496 B.
__global__ void __launch_bounds__(256) dnn_kernel(
    const int* __restrict__ X,
    const float* __restrict__ embf,
    const unsigned short* __restrict__ w1p,
    const float* __restrict__ b1v,
    const unsigned short* __restrict__ w2p,
    const float* __restrict__ b2v,
    const float* __restrict__ w3v,
    const float* __restrict__ b3v,
    const float* __restrict__ att_in,
    float* __restrict__ out)
{
    __shared__ unsigned short ea[2][32 * 72];     // double-buffered [sample 32][64+8pad]
    __shared__ unsigned short h1s[32 * 520];      // h1 [32][512+8pad]; h2 [32][264] aliases
    unsigned short* h2s = h1s;

    const int tid  = threadIdx.x;
    const int wid  = tid >> 6, lane = tid & 63, quad = lane >> 4, l16 = lane & 15;
    const int S0   = blockIdx.x * 32;

    floatx4 C1[2][8];
    #pragma unroll
    for (int mt = 0; mt < 2; ++mt)
        #pragma unroll
        for (int nt = 0; nt < 8; ++nt)
            C1[mt][nt] = (floatx4){0.f, 0.f, 0.f, 0.f};

    const int gs = tid >> 3;        // 0..31 sample for staging
    const int gg = tid & 7;         // 8 floats each

    // prologue: stage field 0 into ea[0]
    {
        int row = X[(S0 + gs) * NF + 0];
        const float4* src = (const float4*)&embf[row * EMB + gg * 8];
        float4 v0 = src[0], v1 = src[1];
        uint4 u;
        u.x = cvt_pk(v0.x, v0.y); u.y = cvt_pk(v0.z, v0.w);
        u.z = cvt_pk(v1.x, v1.y); u.w = cvt_pk(v1.z, v1.w);
        *(uint4*)&ea[0][gs * 72 + gg * 8] = u;
    }
    __syncthreads();

    // ---- phase 1: h1 = emb(32 x 2496) @ W1, K streamed per field, dbuf, 1 sync/iter ---
    for (int f = 0; f < NF; ++f) {
        if (f < NF - 1) {   // stage next field into the other buffer (disjoint from reads)
            int row = X[(S0 + gs) * NF + f + 1] + (f + 1) * VOCAB;
            const float4* src = (const float4*)&embf[row * EMB + gg * 8];
            float4 v0 = src[0], v1 = src[1];
            uint4 u;
            u.x = cvt_pk(v0.x, v0.y); u.y = cvt_pk(v0.z, v0.w);
            u.z = cvt_pk(v1.x, v1.y); u.w = cvt_pk(v1.z, v1.w);
            *(uint4*)&ea[(f + 1) & 1][gs * 72 + gg * 8] = u;
        }
        const unsigned short* eac = ea[f & 1];
        short8 a[2][2];
        #pragma unroll
        for (int mt = 0; mt < 2; ++mt) {
            a[mt][0] = ld8s(&eac[(mt * 16 + l16) * 72 + quad * 8]);
            a[mt][1] = ld8s(&eac[(mt * 16 + l16) * 72 + 32 + quad * 8]);
        }
        #pragma unroll
        for (int nt = 0; nt < 8; ++nt) {
            const unsigned short* bp = w1p + (((wid * 8 + nt) * 78 + f * 2) * 64 + lane) * 8;
            short8 b0 = ld8s(bp);
            short8 b1 = ld8s(bp + 512);
            #pragma unroll
            for (int mt = 0; mt < 2; ++mt) {
                C1[mt][nt] = __builtin_amdgcn_mfma_f32_16x16x32_bf16(a[mt][0], b0, C1[mt][nt], 0, 0, 0);
                C1[mt][nt] = __builtin_amdgcn_mfma_f32_16x16x32_bf16(a[mt][1], b1, C1[mt][nt], 0, 0, 0);
            }
        }
        __syncthreads();   // waves may not drift >1 iter: protects both ea buffers
    }

    // bias + relu, write ALL of h1 to LDS (each wave owns 128 cols)
    #pragma unroll
    for (int nt = 0; nt < 8; ++nt) {
        float bb = b1v[wid * 128 + nt * 16 + l16];
        #pragma unroll
        for (int mt = 0; mt < 2; ++mt) {
            #pragma unroll
            for (int r = 0; r < 4; ++r) {
                float v = fmaxf(C1[mt][nt][r] + bb, 0.f);
                h1s[(mt * 16 + quad * 4 + r) * 520 + wid * 128 + nt * 16 + l16] = f2b(v);
            }
        }
    }
    __syncthreads();

    // ---- phase 2: h2 = h1(32 x 512) @ W2, single pass, wave owns 64 N-cols ------------
    floatx4 C2[2][4];
    #pragma unroll
    for (int mt = 0; mt < 2; ++mt)
        #pragma unroll
        for (int nt = 0; nt < 4; ++nt)
            C2[mt][nt] = (floatx4){0.f, 0.f, 0.f, 0.f};

    #pragma unroll 4
    for (int kk = 0; kk < 16; ++kk) {
        short8 a0 = ld8s(&h1s[(l16) * 520 + kk * 32 + quad * 8]);
        short8 a1 = ld8s(&h1s[(16 + l16) * 520 + kk * 32 + quad * 8]);
        #pragma unroll
        for (int nt = 0; nt < 4; ++nt) {
            short8 b = ld8s(w2p + (((wid * 4 + nt) * 16 + kk) * 64 + lane) * 8);
            C2[0][nt] = __builtin_amdgcn_mfma_f32_16x16x32_bf16(a0, b, C2[0][nt], 0, 0, 0);
            C2[1][nt] = __builtin_amdgcn_mfma_f32_16x16x32_bf16(a1, b, C2[1][nt], 0, 0, 0);
        }
    }
    __syncthreads();    // h1 reads complete -> safe to alias h2s onto h1s

    #pragma unroll
    for (int nt = 0; nt < 4; ++nt) {
        float bb = b2v[wid * 64 + nt * 16 + l16];
        #pragma unroll
        for (int mt = 0; mt < 2; ++mt)
            #pragma unroll
            for (int r = 0; r < 4; ++r)
                h2s[(mt * 16 + quad * 4 + r) * 264 + wid * 64 + nt * 16 + l16] =
                    f2b(fmaxf(C2[mt][nt][r] + bb, 0.f));
    }
    __syncthreads();

    // ---- phase 3: dnn = relu(h2 . W3 + b3); out = sigmoid(att + dnn), f32 -------------
    {
        int s = tid >> 3, part = tid & 7;     // 8 lanes per sample, 32 elems each
        float acc = 0.f;
        #pragma unroll 8
        for (int j = 0; j < 32; ++j) {
            int jj = part * 32 + j;
            acc += b2f(h2s[s * 264 + jj]) * w3v[jj];
        }
        acc += __shfl_xor(acc, 1, 64);
        acc += __shfl_xor(acc, 2, 64);
        acc += __shfl_xor(acc, 4, 64);
        if (part == 0) {
            float dnn = fmaxf(acc + b3v[0], 0.f);
            float v = dnn + att_in[S0 + s];
            out[S0 + s] = 1.f / (1.f + __expf(-v));
        }
    }
}

extern "C" void kernel_launch(void* const* d_in, const int* in_sizes, int n_in,
                              void* d_out, int out_size, void* d_ws, size_t ws_size,
                              hipStream_t stream)
{
    (void)in_sizes; (void)n_in; (void)out_size; (void)ws_size;

    const int*   X    = (const int*)d_in[0];
    const float* emb  = (const float*)d_in[1];
    const float* WQ   = (const float*)d_in[2];
    const float* WK   = (const float*)d_in[3];
    const float* WV   = (const float*)d_in[4];
    const float* WR   = (const float*)d_in[5];
    const float* W1   = (const float*)d_in[6];
    const float* b1   = (const float*)d_in[7];
    const float* W2   = (const float*)d_in[8];
    const float* b2   = (const float*)d_in[9];
    const float* W3   = (const float*)d_in[10];
    const float* b3   = (const float*)d_in[11];
    const float* Wlin = (const float*)d_in[12];

    char* ws = (char*)d_ws;
    float*          att_logit = (float*)ws;                          // 16384 f32 = 64KB
    unsigned short* wqt = (unsigned short*)(ws + 65536);             // 3*4096 shorts each
    unsigned short* wkt = wqt + 3 * 4096;
    unsigned short* wvt = wkt + 3 * 4096;
    unsigned short* wrt = wvt + 3 * 4096;
    unsigned short* w1p = wrt + 3 * 4096;                            // 2496*512 shorts
    unsigned short* w2p = w1p + 2496 * 512;                          // 256*512 shorts

    attw_t<<<192, 256, 0, stream>>>(WQ, WK, WV, WR, wqt, wkt, wvt, wrt);
    w1pack<<<624, 256, 0, stream>>>(W1, w1p);
    w2pack<<<64, 256, 0, stream>>>(W2, w2p);
    attn_kernel<<<4096, 256, 0, stream>>>(X, emb, wqt, wkt, wvt, wrt, Wlin, att_logit);
    dnn_kernel<<<512, 256, 0, stream>>>(X, emb, w1p, b1, w2p, b2, W3, b3, att_logit,
                                        (float*)d_out);
}

// Round 12
// 359.494 us; speedup vs baseline: 1.2229x; 1.1185x over previous
//
#include <hip/hip_runtime.h>
#include <hip/hip_bf16.h>

// AutoInt+MLP fused forward, MI355X gfx950.  Round 27 (consolidation):
//  - attn: ROUND-23 RESTORED VERBATIM (best verified: attn 211us, total 362.8us).
//          2 samples/wave ILP, 128thr/2wave blocks, grid 8192. Structural record:
//          r24 NS=3 (VGPR 160, occ 11%) regressed; r25/r26 barrier-free whole-sample
//          variants (253-259us) regressed vs r23 — barrier-coupled 2-sample is the
//          verified optimum of this family.
//  - prep: attw_t + w1pack + w2pack merged into ONE 880-block dispatcher (bodies
//          unchanged, block-index remap only) — saves 2 stream-serial launch gaps.
//  - dnn : frozen round-10 optimum.
//  HARD RULES: no 2-arg __launch_bounds__; no merged heterogeneous dispatch (attn/dnn);
//  dnn M=64 spills; dnn 512-thr & paired-field regress; attn 2-sample/4-wave FAILED
//  (r19); hoisted GROUPED short8 weight arrays FAILED (r19+r20) — banned; setprio
//  regresses (r21); NS=3 regresses (r24); barrier-free sample-per-wave regresses
//  (r25/r26).

#define NF     39
#define EMB    64
#define NLAYER 3
#define VOCAB  1000
#define FLAT   2496
#define H1     512
#define H2     256

typedef __attribute__((ext_vector_type(8))) short  short8;
typedef __attribute__((ext_vector_type(4))) float  floatx4;

__device__ __forceinline__ short8 ld8s(const unsigned short* p) {
    return *(const short8*)p;
}
__device__ __forceinline__ float b2f(unsigned short h) {
    union { unsigned u; float f; } x; x.u = ((unsigned)h) << 16; return x.f;
}
__device__ __forceinline__ unsigned short f2b(float f) {
    union { float f; unsigned u; } x; x.f = f;
    unsigned u = x.u;
    return (unsigned short)((u + 0x7fffu + ((u >> 16) & 1u)) >> 16);
}
// 2 floats -> packed bf16x2 in ONE VALU op (gfx950 hw cvt, RNE)
__device__ __forceinline__ unsigned cvt_pk(float a, float b) {
#if defined(__gfx950__)
    unsigned r;
    asm("v_cvt_pk_bf16_f32 %0, %1, %2" : "=v"(r) : "v"(a), "v"(b));
    return r;
#else
    return (unsigned)f2b(a) | ((unsigned)f2b(b) << 16);
#endif
}
// 4 packed bf16x2 words -> short8 MFMA operand (register re-arrangement only)
__device__ __forceinline__ short8 pk8(unsigned a, unsigned b, unsigned c, unsigned d) {
    union { unsigned u[4]; short8 s; } x;
    x.u[0] = a; x.u[1] = b; x.u[2] = c; x.u[3] = d;
    return x.s;
}

// ------- merged prep: attw_t (192 blk) + w1pack (624 blk) + w2pack (64 blk) -----------
// 880 blocks x 256 thr; bodies identical to the three original kernels, block-remapped.
__global__ void __launch_bounds__(256) prep_all(
    const float* __restrict__ WQ, const float* __restrict__ WK,
    const float* __restrict__ WV, const float* __restrict__ WR,
    const float* __restrict__ W1, const float* __restrict__ W2,
    unsigned short* __restrict__ wqt, unsigned short* __restrict__ wkt,
    unsigned short* __restrict__ wvt, unsigned short* __restrict__ wrt,
    unsigned short* __restrict__ w1p, unsigned short* __restrict__ w2p)
{
    const int b = blockIdx.x;
    if (b < 192) {
        // ---- attw_t: f32 [L][64 k][64 o] -> bf16 [L][o][k] ----------------------------
        int idx = b * 256 + threadIdx.x;            // 192*256 = 49152 = 4*3*4096 exactly
        int mat = idx / 12288;
        int rem = idx % 12288;
        int l   = rem / 4096;
        int ok  = rem % 4096;
        int o = ok >> 6, k = ok & 63;
        const float*    src = (mat == 0) ? WQ : (mat == 1) ? WK : (mat == 2) ? WV : WR;
        unsigned short* dst = (mat == 0) ? wqt : (mat == 1) ? wkt : (mat == 2) ? wvt : wrt;
        dst[l * 4096 + o * 64 + k] = f2b(src[l * 4096 + k * 64 + o]);
    } else if (b < 192 + 624) {
        // ---- w1pack: f32 [2496][512] -> bf16 fragment-linear --------------------------
        int t = (b - 192) * 256 + threadIdx.x;      // 624*256 = 159744 = 2496*64
        int lane = t & 63, grp = t >> 6;            // grp 0..2495
        int ot = grp / 78, kk = grp % 78;
        int q = lane >> 4, n = ot * 16 + (lane & 15);
        int kb = kk * 32 + q * 8;
        unsigned short* dst = w1p + grp * 512 + lane * 8;
        #pragma unroll
        for (int j = 0; j < 8; ++j)
            dst[j] = f2b(W1[(kb + j) * 512 + n]);
    } else {
        // ---- w2pack: f32 [512][256] -> bf16 fragment-linear ---------------------------
        int t = (b - 816) * 256 + threadIdx.x;      // 64*256 = 16384 = 256*64
        int lane = t & 63, grp = t >> 6;            // grp 0..255
        int ot = grp / 16, kk = grp % 16;
        int q = lane >> 4, n = ot * 16 + (lane & 15);
        int kb = kk * 32 + q * 8;
        unsigned short* dst = w2p + grp * 512 + lane * 8;
        #pragma unroll
        for (int j = 0; j < 8; ++j)
            dst[j] = f2b(W2[(kb + j) * 256 + n]);
    }
}

// ------- fused attention: 2 samples/block, 2 waves (wave = head, BOTH samples) --------
// 8192 blocks x 128 thr. LDS: xss 2x6912 + red 16 = 13840 B.
// All of Q/K/V/P live in registers; xss is the only LDS tile (cross-head x).
__global__ void __launch_bounds__(128) attn_kernel(
    const int* __restrict__ X,
    const float* __restrict__ embf,
    const unsigned short* __restrict__ wqt,
    const unsigned short* __restrict__ wkt,
    const unsigned short* __restrict__ wvt,
    const unsigned short* __restrict__ wrt,
    const float* __restrict__ wlinf,
    float* __restrict__ att_out)
{
    __shared__ unsigned short xss[2][48 * 72];     // per sample: [token 48][col 64+8pad]
    __shared__ float red[2][2];                    // [sample][wave]

    const int tid  = threadIdx.x;
    const int wid  = tid >> 6;          // 0..1
    const int lane = tid & 63;
    const int h    = wid;               // head
    const int quad = lane >> 4;
    const int l16  = lane & 15;
    const int samp0 = blockIdx.x * 2;

    // ---- embedding gather: wave fills its head's cols for BOTH samples ----------------
    {
        const int tq = lane >> 4;            // 0..3
        const int cp = (lane & 15) * 2;      // 0,2,..,30
        const int col = h * 32 + cp;
        #pragma unroll
        for (int s = 0; s < 2; ++s) {
            const int* xrow = X + (samp0 + s) * NF;
            #pragma unroll
            for (int t0 = 0; t0 < 48; t0 += 4) {
                int t = t0 + tq;
                unsigned pk = 0;
                if (t < NF) {
                    int row = xrow[t] + t * VOCAB;
                    const float2 v = *(const float2*)&embf[row * EMB + col];
                    pk = cvt_pk(v.x, v.y);
                }
                *(unsigned*)&xss[s][t * 72 + col] = pk;   // rows 39..47 zeroed
            }
        }
    }
    __syncthreads();

    // ---- hoisted per-lane constants ---------------------------------------------------
    const int wro = (h * 32 + l16) * 64 + quad * 8;    // +ot*1024 per 16-row tile
    const unsigned short* wqp = wqt + wro;
    const unsigned short* wkp = wkt + wro;
    const unsigned short* wvq = wvt + wro;
    const unsigned short* wrp = wrt + wro;
    float m2[4];                                       // jt=2 softmax mask (j=32+quad*4+r)
    #pragma unroll
    for (int r = 0; r < 4; ++r)
        m2[r] = (32 + quad * 4 + r < NF) ? 1.f : 0.f;

    for (int layer = 0; layer < NLAYER; ++layer) {
        // ---- xss fragments for both samples (only LDS reads this layer) ---------------
        short8 xf[2][3][2];
        #pragma unroll
        for (int s = 0; s < 2; ++s)
            #pragma unroll
            for (int tt = 0; tt < 3; ++tt)
                #pragma unroll
                for (int kk = 0; kk < 2; ++kk)
                    xf[s][tt][kk] = ld8s(&xss[s][(tt * 16 + l16) * 72 + kk * 32 + quad * 8]);

        __syncthreads();   // all waves consumed xss -> writeback at end is race-free

        // ---- Q,K projections, weights SHARED across samples ---------------------------
        unsigned qw[2][2][3][2], kw[2][2][3][2];   // [s][ot][tt][word]
        #pragma unroll
        for (int mat = 0; mat < 2; ++mat) {
            const unsigned short* wt = mat ? wkp : wqp;
            #pragma unroll
            for (int ot = 0; ot < 2; ++ot) {
                short8 w0 = ld8s(wt + ot * 1024);
                short8 w1 = ld8s(wt + ot * 1024 + 32);
                #pragma unroll
                for (int s = 0; s < 2; ++s)
                    #pragma unroll
                    for (int tt = 0; tt < 3; ++tt) {
                        floatx4 c = {0.f, 0.f, 0.f, 0.f};
                        c = __builtin_amdgcn_mfma_f32_16x16x32_bf16(w0, xf[s][tt][0], c, 0, 0, 0);
                        c = __builtin_amdgcn_mfma_f32_16x16x32_bf16(w1, xf[s][tt][1], c, 0, 0, 0);
                        if (mat == 0) {
                            qw[s][ot][tt][0] = cvt_pk(c[0], c[1]);
                            qw[s][ot][tt][1] = cvt_pk(c[2], c[3]);
                        } else {
                            kw[s][ot][tt][0] = cvt_pk(c[0], c[1]);
                            kw[s][ot][tt][1] = cvt_pk(c[2], c[3]);
                        }
                    }
            }
        }

        // ---- R projection -> O init (weights shared) ----------------------------------
        floatx4 O[2][2][3];                         // [s][dt][it]
        #pragma unroll
        for (int dt = 0; dt < 2; ++dt) {
            short8 w0 = ld8s(wrp + dt * 1024);
            short8 w1 = ld8s(wrp + dt * 1024 + 32);
            #pragma unroll
            for (int s = 0; s < 2; ++s)
                #pragma unroll
                for (int it = 0; it < 3; ++it) {
                    floatx4 c = {0.f, 0.f, 0.f, 0.f};
                    c = __builtin_amdgcn_mfma_f32_16x16x32_bf16(w0, xf[s][it][0], c, 0, 0, 0);
                    c = __builtin_amdgcn_mfma_f32_16x16x32_bf16(w1, xf[s][it][1], c, 0, 0, 0);
                    O[s][dt][it] = c;
                }
        }

        // ---- V projection -> vw (weights shared; xf dies here) ------------------------
        unsigned vw[2][3][2][2];                    // [s][mt][nt][word]
        #pragma unroll
        for (int nt = 0; nt < 2; ++nt) {
            short8 w0 = ld8s(wvq + nt * 1024);
            short8 w1 = ld8s(wvq + nt * 1024 + 32);
            #pragma unroll
            for (int s = 0; s < 2; ++s)
                #pragma unroll
                for (int mt = 0; mt < 3; ++mt) {
                    floatx4 c = {0.f, 0.f, 0.f, 0.f};
                    c = __builtin_amdgcn_mfma_f32_16x16x32_bf16(xf[s][mt][0], w0, c, 0, 0, 0);
                    c = __builtin_amdgcn_mfma_f32_16x16x32_bf16(xf[s][mt][1], w1, c, 0, 0, 0);
                    vw[s][mt][nt][0] = cvt_pk(c[0], c[1]);
                    vw[s][mt][nt][1] = cvt_pk(c[2], c[3]);
                }
        }

        // ---- per sample: S^T then softmax (ONE ST tensor live at a time) --------------
        unsigned pw[2][3][3][2];                    // [s][jt][it][word]
        #pragma unroll
        for (int s = 0; s < 2; ++s) {
            floatx4 ST[3][3];
            #pragma unroll
            for (int jt = 0; jt < 3; ++jt) {
                short8 a = pk8(kw[s][0][jt][0], kw[s][0][jt][1], kw[s][1][jt][0], kw[s][1][jt][1]);
                #pragma unroll
                for (int it = 0; it < 3; ++it) {
                    short8 b = pk8(qw[s][0][it][0], qw[s][0][it][1], qw[s][1][it][0], qw[s][1][it][1]);
                    floatx4 z = {0.f, 0.f, 0.f, 0.f};
                    ST[jt][it] = __builtin_amdgcn_mfma_f32_16x16x32_bf16(a, b, z, 0, 0, 0);
                }
            }
            #pragma unroll
            for (int it = 0; it < 3; ++it) {
                float p[3][4];
                float sum = 0.f;
                #pragma unroll
                for (int jt = 0; jt < 3; ++jt)
                    #pragma unroll
                    for (int r = 0; r < 4; ++r) {
                        float e = __expf(ST[jt][it][r]);
                        if (jt == 2) e *= m2[r];
                        p[jt][r] = e;
                        sum += e;
                    }
                sum += __shfl_xor(sum, 16, 64);
                sum += __shfl_xor(sum, 32, 64);
                float inv = 1.0f / sum;
                #pragma unroll
                for (int jt = 0; jt < 3; ++jt) {
                    pw[s][jt][it][0] = cvt_pk(p[jt][0] * inv, p[jt][1] * inv);
                    pw[s][jt][it][1] = cvt_pk(p[jt][2] * inv, p[jt][3] * inv);
                }
            }
        }

        // ---- O^T += V^T @ P^T per sample ----------------------------------------------
        #pragma unroll
        for (int s = 0; s < 2; ++s)
            #pragma unroll
            for (int dt = 0; dt < 2; ++dt) {
                short8 a01 = pk8(vw[s][0][dt][0], vw[s][0][dt][1], vw[s][1][dt][0], vw[s][1][dt][1]);
                short8 a2  = pk8(vw[s][2][dt][0], vw[s][2][dt][1], 0u, 0u);
                #pragma unroll
                for (int it = 0; it < 3; ++it) {
                    short8 b01 = pk8(pw[s][0][it][0], pw[s][0][it][1], pw[s][1][it][0], pw[s][1][it][1]);
                    short8 b2  = pk8(pw[s][2][it][0], pw[s][2][it][1], 0u, 0u);
                    O[s][dt][it] = __builtin_amdgcn_mfma_f32_16x16x32_bf16(a01, b01, O[s][dt][it], 0, 0, 0);
                    O[s][dt][it] = __builtin_amdgcn_mfma_f32_16x16x32_bf16(a2,  b2,  O[s][dt][it], 0, 0, 0);
                }
            }

        // ---- next x = relu(O^T): write xss[s][tok][d] ---------------------------------
        #pragma unroll
        for (int s = 0; s < 2; ++s)
            #pragma unroll
            for (int dt = 0; dt < 2; ++dt)
                #pragma unroll
                for (int it = 0; it < 3; ++it) {
                    uint2 w;
                    w.x = cvt_pk(fmaxf(O[s][dt][it][0], 0.f), fmaxf(O[s][dt][it][1], 0.f));
                    w.y = cvt_pk(fmaxf(O[s][dt][it][2], 0.f), fmaxf(O[s][dt][it][3], 0.f));
                    *(uint2*)&xss[s][(it * 16 + l16) * 72 + h * 32 + dt * 16 + quad * 4] = w;
                }

        __syncthreads();   // xss rewritten before next layer's xf loads

        wqp += 4096; wkp += 4096; wvq += 4096; wrp += 4096;   // next layer's weights
    }

    // ---- att logit: relu( att_flat . Wlin ), both samples -----------------------------
    {
        const int c = lane & 31, tp = lane >> 5;
        const int col = h * 32 + c;
        #pragma unroll
        for (int s = 0; s < 2; ++s) {
            float acc = 0.f;
            for (int t0 = 0; t0 < 40; t0 += 2) {
                int t = t0 + tp;
                if (t < NF)
                    acc += b2f(xss[s][t * 72 + col]) * wlinf[t * EMB + col];
            }
            #pragma unroll
            for (int off = 1; off < 64; off <<= 1)
                acc += __shfl_xor(acc, off, 64);
            if (lane == 0) red[s][wid] = acc;
        }
        __syncthreads();
        if (tid == 0) {
            att_out[samp0]     = fmaxf(red[0][0] + red[0][1], 0.f);
            att_out[samp0 + 1] = fmaxf(red[1][0] + red[1][1], 0.f);
        }
    }
}

// ------- DNN (ROUND-10 VERBATIM, frozen optimum): 32-sample tile, packed B-loads ------
// 512 blocks x 256 thr. LDS: ea 9216 + h1s 33280 = 42496 B.
__global__ void __launch_bounds__(256) dnn_kernel(
    const int* __restrict__ X,
    const float* __restrict__ embf,
    const unsigned short* __restrict__ w1p,
    const float* __restrict__ b1v,
    const unsigned short* __restrict__ w2p,
    const float* __restrict__ b2v,
    const float* __restrict__ w3v,
    const float* __restrict__ b3v,
    const float* __restrict__ att_in,
    float* __restrict__ out)
{
    __shared__ unsigned short ea[2][32 * 72];     // double-buffered [sample 32][64+8pad]
    __shared__ unsigned short h1s[32 * 520];      // h1 [32][512+8pad]; h2 [32][264] aliases
    unsigned short* h2s = h1s;

    const int tid  = threadIdx.x;
    const int wid  = tid >> 6, lane = tid & 63, quad = lane >> 4, l16 = lane & 15;
    const int S0   = blockIdx.x * 32;

    floatx4 C1[2][8];
    #pragma unroll
    for (int mt = 0; mt < 2; ++mt)
        #pragma unroll
        for (int nt = 0; nt < 8; ++nt)
            C1[mt][nt] = (floatx4){0.f, 0.f, 0.f, 0.f};

    const int gs = tid >> 3;        // 0..31 sample for staging
    const int gg = tid & 7;         // 8 floats each

    // prologue: stage field 0 into ea[0]
    {
        int row = X[(S0 + gs) * NF + 0];
        const float4* src = (const float4*)&embf[row * EMB + gg * 8];
        float4 v0 = src[0], v1 = src[1];
        uint4 u;
        u.x = cvt_pk(v0.x, v0.y); u.y = cvt_pk(v0.z, v0.w);
        u.z = cvt_pk(v1.x, v1.y); u.w = cvt_pk(v1.z, v1.w);
        *(uint4*)&ea[0][gs * 72 + gg * 8] = u;
    }
    __syncthreads();

    // ---- phase 1: h1 = emb(32 x 2496) @ W1, K streamed per field, dbuf, 1 sync/iter ---
    for (int f = 0; f < NF; ++f) {
        if (f < NF - 1) {   // stage next field into the other buffer (disjoint from reads)
            int row = X[(S0 + gs) * NF + f + 1] + (f + 1) * VOCAB;
            const float4* src = (const float4*)&embf[row * EMB + gg * 8];
            float4 v0 = src[0], v1 = src[1];
            uint4 u;
            u.x = cvt_pk(v0.x, v0.y); u.y = cvt_pk(v0.z, v0.w);
            u.z = cvt_pk(v1.x, v1.y); u.w = cvt_pk(v1.z, v1.w);
            *(uint4*)&ea[(f + 1) & 1][gs * 72 + gg * 8] = u;
        }
        const unsigned short* eac = ea[f & 1];
        short8 a[2][2];
        #pragma unroll
        for (int mt = 0; mt < 2; ++mt) {
            a[mt][0] = ld8s(&eac[(mt * 16 + l16) * 72 + quad * 8]);
            a[mt][1] = ld8s(&eac[(mt * 16 + l16) * 72 + 32 + quad * 8]);
        }
        #pragma unroll
        for (int nt = 0; nt < 8; ++nt) {
            const unsigned short* bp = w1p + (((wid * 8 + nt) * 78 + f * 2) * 64 + lane) * 8;
            short8 b0 = ld8s(bp);
            short8 b1 = ld8s(bp + 512);
            #pragma unroll
            for (int mt = 0; mt < 2; ++mt) {
                C1[mt][nt] = __builtin_amdgcn_mfma_f32_16x16x32_bf16(a[mt][0], b0, C1[mt][nt], 0, 0, 0);
                C1[mt][nt] = __builtin_amdgcn_mfma_f32_16x16x32_bf16(a[mt][1], b1, C1[mt][nt], 0, 0, 0);
            }
        }
        __syncthreads();   // waves may not drift >1 iter: protects both ea buffers
    }

    // bias + relu, write ALL of h1 to LDS (each wave owns 128 cols)
    #pragma unroll
    for (int nt = 0; nt < 8; ++nt) {
        float bb = b1v[wid * 128 + nt * 16 + l16];
        #pragma unroll
        for (int mt = 0; mt < 2; ++mt) {
            #pragma unroll
            for (int r = 0; r < 4; ++r) {
                float v = fmaxf(C1[mt][nt][r] + bb, 0.f);
                h1s[(mt * 16 + quad * 4 + r) * 520 + wid * 128 + nt * 16 + l16] = f2b(v);
            }
        }
    }
    __syncthreads();

    // ---- phase 2: h2 = h1(32 x 512) @ W2, single pass, wave owns 64 N-cols ------------
    floatx4 C2[2][4];
    #pragma unroll
    for (int mt = 0; mt < 2; ++mt)
        #pragma unroll
        for (int nt = 0; nt < 4; ++nt)
            C2[mt][nt] = (floatx4){0.f, 0.f, 0.f, 0.f};

    #pragma unroll 4
    for (int kk = 0; kk < 16; ++kk) {
        short8 a0 = ld8s(&h1s[(l16) * 520 + kk * 32 + quad * 8]);
        short8 a1 = ld8s(&h1s[(16 + l16) * 520 + kk * 32 + quad * 8]);
        #pragma unroll
        for (int nt = 0; nt < 4; ++nt) {
            short8 b = ld8s(w2p + (((wid * 4 + nt) * 16 + kk) * 64 + lane) * 8);
            C2[0][nt] = __builtin_amdgcn_mfma_f32_16x16x32_bf16(a0, b, C2[0][nt], 0, 0, 0);
            C2[1][nt] = __builtin_amdgcn_mfma_f32_16x16x32_bf16(a1, b, C2[1][nt], 0, 0, 0);
        }
    }
    __syncthreads();    // h1 reads complete -> safe to alias h2s onto h1s

    #pragma unroll
    for (int nt = 0; nt < 4; ++nt) {
        float bb = b2v[wid * 64 + nt * 16 + l16];
        #pragma unroll
        for (int mt = 0; mt < 2; ++mt)
            #pragma unroll
            for (int r = 0; r < 4; ++r)
                h2s[(mt * 16 + quad * 4 + r) * 264 + wid * 64 + nt * 16 + l16] =
                    f2b(fmaxf(C2[mt][nt][r] + bb, 0.f));
    }
    __syncthreads();

    // ---- phase 3: dnn = relu(h2 . W3 + b3); out = sigmoid(att + dnn), f32 -------------
    {
        int s = tid >> 3, part = tid & 7;     // 8 lanes per sample, 32 elems each
        float acc = 0.f;
        #pragma unroll 8
        for (int j = 0; j < 32; ++j) {
            int jj = part * 32 + j;
            acc += b2f(h2s[s * 264 + jj]) * w3v[jj];
        }
        acc += __shfl_xor(acc, 1, 64);
        acc += __shfl_xor(acc, 2, 64);
        acc += __shfl_xor(acc, 4, 64);
        if (part == 0) {
            float dnn = fmaxf(acc + b3v[0], 0.f);
            float v = dnn + att_in[S0 + s];
            out[S0 + s] = 1.f / (1.f + __expf(-v));
        }
    }
}

extern "C" void kernel_launch(void* const* d_in, const int* in_sizes, int n_in,
                              void* d_out, int out_size, void* d_ws, size_t ws_size,
                              hipStream_t stream)
{
    (void)in_sizes; (void)n_in; (void)out_size; (void)ws_size;

    const int*   X    = (const int*)d_in[0];
    const float* emb  = (const float*)d_in[1];
    const float* WQ   = (const float*)d_in[2];
    const float* WK   = (const float*)d_in[3];
    const float* WV   = (const float*)d_in[4];
    const float* WR   = (const float*)d_in[5];
    const float* W1   = (const float*)d_in[6];
    const float* b1   = (const float*)d_in[7];
    const float* W2   = (const float*)d_in[8];
    const float* b2   = (const float*)d_in[9];
    const float* W3   = (const float*)d_in[10];
    const float* b3   = (const float*)d_in[11];
    const float* Wlin = (const float*)d_in[12];

    char* ws = (char*)d_ws;
    float*          att_logit = (float*)ws;                          // 16384 f32 = 64KB
    unsigned short* wqt = (unsigned short*)(ws + 65536);             // 3*4096 shorts each
    unsigned short* wkt = wqt + 3 * 4096;
    unsigned short* wvt = wkt + 3 * 4096;
    unsigned short* wrt = wvt + 3 * 4096;
    unsigned short* w1p = wrt + 3 * 4096;                            // 2496*512 shorts
    unsigned short* w2p = w1p + 2496 * 512;                          // 256*512 shorts

    prep_all<<<880, 256, 0, stream>>>(WQ, WK, WV, WR, W1, W2,
                                      wqt, wkt, wvt, wrt, w1p, w2p);
    attn_kernel<<<8192, 128, 0, stream>>>(X, emb, wqt, wkt, wvt, wrt, Wlin, att_logit);
    dnn_kernel<<<512, 256, 0, stream>>>(X, emb, w1p, b1, w2p, b2, W3, b3, att_logit,
                                        (float*)d_out);
}

// Round 13
// 349.143 us; speedup vs baseline: 1.2592x; 1.0296x over previous
//
#include <hip/hip_runtime.h>
#include <hip/hip_bf16.h>

// AutoInt+MLP fused forward, MI355X gfx950.  Round 28:
//  - attn: r23/r27 structure + DOUBLE-BUFFERED xss. Barrier #1 of each layer
//          (read->write WAR guard on the same buffer) deleted by alternating
//          read/write buffers per layer: 7 barriers -> 4 for the whole kernel,
//          waves drift a full compute phase instead of locking twice per layer.
//          LDS 13.8 -> 27.7 KB (cap 5 blocks/CU = 10 waves > measured ~7: no bind).
//          Numerics bit-identical (same ops/order, only LDS addresses alternate).
//  - prep: merged single dispatcher (r27 verified, ~3us).
//  - dnn : frozen round-10 optimum.
//  HARD RULES: no 2-arg __launch_bounds__; no merged heterogeneous dispatch (attn/dnn);
//  dnn M=64 spills; dnn 512-thr & paired-field regress; attn 2-sample/4-wave FAILED
//  (r19); hoisted GROUPED short8 weight arrays FAILED (r19+r20) — banned; setprio
//  regresses (r21); NS=3 regresses (r24); barrier-free sample-per-wave regresses
//  (r25/r26); attn run-to-run variance ~±5% (r23 211us vs r27 222us, same source).

#define NF     39
#define EMB    64
#define NLAYER 3
#define VOCAB  1000
#define FLAT   2496
#define H1     512
#define H2     256

typedef __attribute__((ext_vector_type(8))) short  short8;
typedef __attribute__((ext_vector_type(4))) float  floatx4;

__device__ __forceinline__ short8 ld8s(const unsigned short* p) {
    return *(const short8*)p;
}
__device__ __forceinline__ float b2f(unsigned short h) {
    union { unsigned u; float f; } x; x.u = ((unsigned)h) << 16; return x.f;
}
__device__ __forceinline__ unsigned short f2b(float f) {
    union { float f; unsigned u; } x; x.f = f;
    unsigned u = x.u;
    return (unsigned short)((u + 0x7fffu + ((u >> 16) & 1u)) >> 16);
}
// 2 floats -> packed bf16x2 in ONE VALU op (gfx950 hw cvt, RNE)
__device__ __forceinline__ unsigned cvt_pk(float a, float b) {
#if defined(__gfx950__)
    unsigned r;
    asm("v_cvt_pk_bf16_f32 %0, %1, %2" : "=v"(r) : "v"(a), "v"(b));
    return r;
#else
    return (unsigned)f2b(a) | ((unsigned)f2b(b) << 16);
#endif
}
// 4 packed bf16x2 words -> short8 MFMA operand (register re-arrangement only)
__device__ __forceinline__ short8 pk8(unsigned a, unsigned b, unsigned c, unsigned d) {
    union { unsigned u[4]; short8 s; } x;
    x.u[0] = a; x.u[1] = b; x.u[2] = c; x.u[3] = d;
    return x.s;
}

// ------- merged prep: attw_t (192 blk) + w1pack (624 blk) + w2pack (64 blk) -----------
// 880 blocks x 256 thr; bodies identical to the three original kernels, block-remapped.
__global__ void __launch_bounds__(256) prep_all(
    const float* __restrict__ WQ, const float* __restrict__ WK,
    const float* __restrict__ WV, const float* __restrict__ WR,
    const float* __restrict__ W1, const float* __restrict__ W2,
    unsigned short* __restrict__ wqt, unsigned short* __restrict__ wkt,
    unsigned short* __restrict__ wvt, unsigned short* __restrict__ wrt,
    unsigned short* __restrict__ w1p, unsigned short* __restrict__ w2p)
{
    const int b = blockIdx.x;
    if (b < 192) {
        // ---- attw_t: f32 [L][64 k][64 o] -> bf16 [L][o][k] ----------------------------
        int idx = b * 256 + threadIdx.x;            // 192*256 = 49152 = 4*3*4096 exactly
        int mat = idx / 12288;
        int rem = idx % 12288;
        int l   = rem / 4096;
        int ok  = rem % 4096;
        int o = ok >> 6, k = ok & 63;
        const float*    src = (mat == 0) ? WQ : (mat == 1) ? WK : (mat == 2) ? WV : WR;
        unsigned short* dst = (mat == 0) ? wqt : (mat == 1) ? wkt : (mat == 2) ? wvt : wrt;
        dst[l * 4096 + o * 64 + k] = f2b(src[l * 4096 + k * 64 + o]);
    } else if (b < 192 + 624) {
        // ---- w1pack: f32 [2496][512] -> bf16 fragment-linear --------------------------
        int t = (b - 192) * 256 + threadIdx.x;      // 624*256 = 159744 = 2496*64
        int lane = t & 63, grp = t >> 6;            // grp 0..2495
        int ot = grp / 78, kk = grp % 78;
        int q = lane >> 4, n = ot * 16 + (lane & 15);
        int kb = kk * 32 + q * 8;
        unsigned short* dst = w1p + grp * 512 + lane * 8;
        #pragma unroll
        for (int j = 0; j < 8; ++j)
            dst[j] = f2b(W1[(kb + j) * 512 + n]);
    } else {
        // ---- w2pack: f32 [512][256] -> bf16 fragment-linear ---------------------------
        int t = (b - 816) * 256 + threadIdx.x;      // 64*256 = 16384 = 256*64
        int lane = t & 63, grp = t >> 6;            // grp 0..255
        int ot = grp / 16, kk = grp % 16;
        int q = lane >> 4, n = ot * 16 + (lane & 15);
        int kb = kk * 32 + q * 8;
        unsigned short* dst = w2p + grp * 512 + lane * 8;
        #pragma unroll
        for (int j = 0; j < 8; ++j)
            dst[j] = f2b(W2[(kb + j) * 256 + n]);
    }
}

// ------- fused attention: 2 samples/block, 2 waves (wave = head, BOTH samples) --------
// 8192 blocks x 128 thr. LDS: xss 2(buf) x 2(sample) x 6912 + red 16 = 27664 B.
// Double-buffered xss: layer L reads buf L&1, writes buf (L+1)&1 -> ONE barrier/layer.
__global__ void __launch_bounds__(128) attn_kernel(
    const int* __restrict__ X,
    const float* __restrict__ embf,
    const unsigned short* __restrict__ wqt,
    const unsigned short* __restrict__ wkt,
    const unsigned short* __restrict__ wvt,
    const unsigned short* __restrict__ wrt,
    const float* __restrict__ wlinf,
    float* __restrict__ att_out)
{
    __shared__ unsigned short xss[2][2][48 * 72];  // [buf][sample][token 48][col 64+8pad]
    __shared__ float red[2][2];                    // [sample][wave]

    const int tid  = threadIdx.x;
    const int wid  = tid >> 6;          // 0..1
    const int lane = tid & 63;
    const int h    = wid;               // head
    const int quad = lane >> 4;
    const int l16  = lane & 15;
    const int samp0 = blockIdx.x * 2;

    // ---- embedding gather: wave fills its head's cols for BOTH samples into buf 0 -----
    {
        const int tq = lane >> 4;            // 0..3
        const int cp = (lane & 15) * 2;      // 0,2,..,30
        const int col = h * 32 + cp;
        #pragma unroll
        for (int s = 0; s < 2; ++s) {
            const int* xrow = X + (samp0 + s) * NF;
            #pragma unroll
            for (int t0 = 0; t0 < 48; t0 += 4) {
                int t = t0 + tq;
                unsigned pk = 0;
                if (t < NF) {
                    int row = xrow[t] + t * VOCAB;
                    const float2 v = *(const float2*)&embf[row * EMB + col];
                    pk = cvt_pk(v.x, v.y);
                }
                *(unsigned*)&xss[0][s][t * 72 + col] = pk;   // rows 39..47 zeroed
            }
        }
    }
    __syncthreads();

    // ---- hoisted per-lane constants ---------------------------------------------------
    const int wro = (h * 32 + l16) * 64 + quad * 8;    // +ot*1024 per 16-row tile
    const unsigned short* wqp = wqt + wro;
    const unsigned short* wkp = wkt + wro;
    const unsigned short* wvq = wvt + wro;
    const unsigned short* wrp = wrt + wro;
    float m2[4];                                       // jt=2 softmax mask (j=32+quad*4+r)
    #pragma unroll
    for (int r = 0; r < 4; ++r)
        m2[r] = (32 + quad * 4 + r < NF) ? 1.f : 0.f;

    for (int layer = 0; layer < NLAYER; ++layer) {
        const int rb = layer & 1, wb = rb ^ 1;

        // ---- xss fragments for both samples (reads buf rb; no barrier needed after:
        //      this layer's writes go to buf wb, disjoint) ------------------------------
        short8 xf[2][3][2];
        #pragma unroll
        for (int s = 0; s < 2; ++s)
            #pragma unroll
            for (int tt = 0; tt < 3; ++tt)
                #pragma unroll
                for (int kk = 0; kk < 2; ++kk)
                    xf[s][tt][kk] = ld8s(&xss[rb][s][(tt * 16 + l16) * 72 + kk * 32 + quad * 8]);

        // ---- Q,K projections, weights SHARED across samples ---------------------------
        unsigned qw[2][2][3][2], kw[2][2][3][2];   // [s][ot][tt][word]
        #pragma unroll
        for (int mat = 0; mat < 2; ++mat) {
            const unsigned short* wt = mat ? wkp : wqp;
            #pragma unroll
            for (int ot = 0; ot < 2; ++ot) {
                short8 w0 = ld8s(wt + ot * 1024);
                short8 w1 = ld8s(wt + ot * 1024 + 32);
                #pragma unroll
                for (int s = 0; s < 2; ++s)
                    #pragma unroll
                    for (int tt = 0; tt < 3; ++tt) {
                        floatx4 c = {0.f, 0.f, 0.f, 0.f};
                        c = __builtin_amdgcn_mfma_f32_16x16x32_bf16(w0, xf[s][tt][0], c, 0, 0, 0);
                        c = __builtin_amdgcn_mfma_f32_16x16x32_bf16(w1, xf[s][tt][1], c, 0, 0, 0);
                        if (mat == 0) {
                            qw[s][ot][tt][0] = cvt_pk(c[0], c[1]);
                            qw[s][ot][tt][1] = cvt_pk(c[2], c[3]);
                        } else {
                            kw[s][ot][tt][0] = cvt_pk(c[0], c[1]);
                            kw[s][ot][tt][1] = cvt_pk(c[2], c[3]);
                        }
                    }
            }
        }

        // ---- R projection -> O init (weights shared) ----------------------------------
        floatx4 O[2][2][3];                         // [s][dt][it]
        #pragma unroll
        for (int dt = 0; dt < 2; ++dt) {
            short8 w0 = ld8s(wrp + dt * 1024);
            short8 w1 = ld8s(wrp + dt * 1024 + 32);
            #pragma unroll
            for (int s = 0; s < 2; ++s)
                #pragma unroll
                for (int it = 0; it < 3; ++it) {
                    floatx4 c = {0.f, 0.f, 0.f, 0.f};
                    c = __builtin_amdgcn_mfma_f32_16x16x32_bf16(w0, xf[s][it][0], c, 0, 0, 0);
                    c = __builtin_amdgcn_mfma_f32_16x16x32_bf16(w1, xf[s][it][1], c, 0, 0, 0);
                    O[s][dt][it] = c;
                }
        }

        // ---- V projection -> vw (weights shared; xf dies here) ------------------------
        unsigned vw[2][3][2][2];                    // [s][mt][nt][word]
        #pragma unroll
        for (int nt = 0; nt < 2; ++nt) {
            short8 w0 = ld8s(wvq + nt * 1024);
            short8 w1 = ld8s(wvq + nt * 1024 + 32);
            #pragma unroll
            for (int s = 0; s < 2; ++s)
                #pragma unroll
                for (int mt = 0; mt < 3; ++mt) {
                    floatx4 c = {0.f, 0.f, 0.f, 0.f};
                    c = __builtin_amdgcn_mfma_f32_16x16x32_bf16(xf[s][mt][0], w0, c, 0, 0, 0);
                    c = __builtin_amdgcn_mfma_f32_16x16x32_bf16(xf[s][mt][1], w1, c, 0, 0, 0);
                    vw[s][mt][nt][0] = cvt_pk(c[0], c[1]);
                    vw[s][mt][nt][1] = cvt_pk(c[2], c[3]);
                }
        }

        // ---- per sample: S^T then softmax (ONE ST tensor live at a time) --------------
        unsigned pw[2][3][3][2];                    // [s][jt][it][word]
        #pragma unroll
        for (int s = 0; s < 2; ++s) {
            floatx4 ST[3][3];
            #pragma unroll
            for (int jt = 0; jt < 3; ++jt) {
                short8 a = pk8(kw[s][0][jt][0], kw[s][0][jt][1], kw[s][1][jt][0], kw[s][1][jt][1]);
                #pragma unroll
                for (int it = 0; it < 3; ++it) {
                    short8 b = pk8(qw[s][0][it][0], qw[s][0][it][1], qw[s][1][it][0], qw[s][1][it][1]);
                    floatx4 z = {0.f, 0.f, 0.f, 0.f};
                    ST[jt][it] = __builtin_amdgcn_mfma_f32_16x16x32_bf16(a, b, z, 0, 0, 0);
                }
            }
            #pragma unroll
            for (int it = 0; it < 3; ++it) {
                float p[3][4];
                float sum = 0.f;
                #pragma unroll
                for (int jt = 0; jt < 3; ++jt)
                    #pragma unroll
                    for (int r = 0; r < 4; ++r) {
                        float e = __expf(ST[jt][it][r]);
                        if (jt == 2) e *= m2[r];
                        p[jt][r] = e;
                        sum += e;
                    }
                sum += __shfl_xor(sum, 16, 64);
                sum += __shfl_xor(sum, 32, 64);
                float inv = 1.0f / sum;
                #pragma unroll
                for (int jt = 0; jt < 3; ++jt) {
                    pw[s][jt][it][0] = cvt_pk(p[jt][0] * inv, p[jt][1] * inv);
                    pw[s][jt][it][1] = cvt_pk(p[jt][2] * inv, p[jt][3] * inv);
                }
            }
        }

        // ---- O^T += V^T @ P^T per sample ----------------------------------------------
        #pragma unroll
        for (int s = 0; s < 2; ++s)
            #pragma unroll
            for (int dt = 0; dt < 2; ++dt) {
                short8 a01 = pk8(vw[s][0][dt][0], vw[s][0][dt][1], vw[s][1][dt][0], vw[s][1][dt][1]);
                short8 a2  = pk8(vw[s][2][dt][0], vw[s][2][dt][1], 0u, 0u);
                #pragma unroll
                for (int it = 0; it < 3; ++it) {
                    short8 b01 = pk8(pw[s][0][it][0], pw[s][0][it][1], pw[s][1][it][0], pw[s][1][it][1]);
                    short8 b2  = pk8(pw[s][2][it][0], pw[s][2][it][1], 0u, 0u);
                    O[s][dt][it] = __builtin_amdgcn_mfma_f32_16x16x32_bf16(a01, b01, O[s][dt][it], 0, 0, 0);
                    O[s][dt][it] = __builtin_amdgcn_mfma_f32_16x16x32_bf16(a2,  b2,  O[s][dt][it], 0, 0, 0);
                }
            }

        // ---- next x = relu(O^T): write xss[wb][s][tok][d] (disjoint from reads) -------
        #pragma unroll
        for (int s = 0; s < 2; ++s)
            #pragma unroll
            for (int dt = 0; dt < 2; ++dt)
                #pragma unroll
                for (int it = 0; it < 3; ++it) {
                    uint2 w;
                    w.x = cvt_pk(fmaxf(O[s][dt][it][0], 0.f), fmaxf(O[s][dt][it][1], 0.f));
                    w.y = cvt_pk(fmaxf(O[s][dt][it][2], 0.f), fmaxf(O[s][dt][it][3], 0.f));
                    *(uint2*)&xss[wb][s][(it * 16 + l16) * 72 + h * 32 + dt * 16 + quad * 4] = w;
                }

        __syncthreads();   // buf wb complete before next layer (or logit) reads it
    }

    // ---- att logit: relu( att_flat . Wlin ), both samples (x lives in buf NLAYER&1) ---
    {
        const unsigned short* xfin0 = xss[NLAYER & 1][0];
        const unsigned short* xfin1 = xss[NLAYER & 1][1];
        const int c = lane & 31, tp = lane >> 5;
        const int col = h * 32 + c;
        #pragma unroll
        for (int s = 0; s < 2; ++s) {
            const unsigned short* xf = s ? xfin1 : xfin0;
            float acc = 0.f;
            for (int t0 = 0; t0 < 40; t0 += 2) {
                int t = t0 + tp;
                if (t < NF)
                    acc += b2f(xf[t * 72 + col]) * wlinf[t * EMB + col];
            }
            #pragma unroll
            for (int off = 1; off < 64; off <<= 1)
                acc += __shfl_xor(acc, off, 64);
            if (lane == 0) red[s][wid] = acc;
        }
        __syncthreads();
        if (tid == 0) {
            att_out[samp0]     = fmaxf(red[0][0] + red[0][1], 0.f);
            att_out[samp0 + 1] = fmaxf(red[1][0] + red[1][1], 0.f);
        }
    }
}

// ------- DNN (ROUND-10 VERBATIM, frozen optimum): 32-sample tile, packed B-loads ------
// 512 blocks x 256 thr. LDS: ea 9216 + h1s 33280 = 42496 B.
__global__ void __launch_bounds__(256) dnn_kernel(
    const int* __restrict__ X,
    const float* __restrict__ embf,
    const unsigned short* __restrict__ w1p,
    const float* __restrict__ b1v,
    const unsigned short* __restrict__ w2p,
    const float* __restrict__ b2v,
    const float* __restrict__ w3v,
    const float* __restrict__ b3v,
    const float* __restrict__ att_in,
    float* __restrict__ out)
{
    __shared__ unsigned short ea[2][32 * 72];     // double-buffered [sample 32][64+8pad]
    __shared__ unsigned short h1s[32 * 520];      // h1 [32][512+8pad]; h2 [32][264] aliases
    unsigned short* h2s = h1s;

    const int tid  = threadIdx.x;
    const int wid  = tid >> 6, lane = tid & 63, quad = lane >> 4, l16 = lane & 15;
    const int S0   = blockIdx.x * 32;

    floatx4 C1[2][8];
    #pragma unroll
    for (int mt = 0; mt < 2; ++mt)
        #pragma unroll
        for (int nt = 0; nt < 8; ++nt)
            C1[mt][nt] = (floatx4){0.f, 0.f, 0.f, 0.f};

    const int gs = tid >> 3;        // 0..31 sample for staging
    const int gg = tid & 7;         // 8 floats each

    // prologue: stage field 0 into ea[0]
    {
        int row = X[(S0 + gs) * NF + 0];
        const float4* src = (const float4*)&embf[row * EMB + gg * 8];
        float4 v0 = src[0], v1 = src[1];
        uint4 u;
        u.x = cvt_pk(v0.x, v0.y); u.y = cvt_pk(v0.z, v0.w);
        u.z = cvt_pk(v1.x, v1.y); u.w = cvt_pk(v1.z, v1.w);
        *(uint4*)&ea[0][gs * 72 + gg * 8] = u;
    }
    __syncthreads();

    // ---- phase 1: h1 = emb(32 x 2496) @ W1, K streamed per field, dbuf, 1 sync/iter ---
    for (int f = 0; f < NF; ++f) {
        if (f < NF - 1) {   // stage next field into the other buffer (disjoint from reads)
            int row = X[(S0 + gs) * NF + f + 1] + (f + 1) * VOCAB;
            const float4* src = (const float4*)&embf[row * EMB + gg * 8];
            float4 v0 = src[0], v1 = src[1];
            uint4 u;
            u.x = cvt_pk(v0.x, v0.y); u.y = cvt_pk(v0.z, v0.w);
            u.z = cvt_pk(v1.x, v1.y); u.w = cvt_pk(v1.z, v1.w);
            *(uint4*)&ea[(f + 1) & 1][gs * 72 + gg * 8] = u;
        }
        const unsigned short* eac = ea[f & 1];
        short8 a[2][2];
        #pragma unroll
        for (int mt = 0; mt < 2; ++mt) {
            a[mt][0] = ld8s(&eac[(mt * 16 + l16) * 72 + quad * 8]);
            a[mt][1] = ld8s(&eac[(mt * 16 + l16) * 72 + 32 + quad * 8]);
        }
        #pragma unroll
        for (int nt = 0; nt < 8; ++nt) {
            const unsigned short* bp = w1p + (((wid * 8 + nt) * 78 + f * 2) * 64 + lane) * 8;
            short8 b0 = ld8s(bp);
            short8 b1 = ld8s(bp + 512);
            #pragma unroll
            for (int mt = 0; mt < 2; ++mt) {
                C1[mt][nt] = __builtin_amdgcn_mfma_f32_16x16x32_bf16(a[mt][0], b0, C1[mt][nt], 0, 0, 0);
                C1[mt][nt] = __builtin_amdgcn_mfma_f32_16x16x32_bf16(a[mt][1], b1, C1[mt][nt], 0, 0, 0);
            }
        }
        __syncthreads();   // waves may not drift >1 iter: protects both ea buffers
    }

    // bias + relu, write ALL of h1 to LDS (each wave owns 128 cols)
    #pragma unroll
    for (int nt = 0; nt < 8; ++nt) {
        float bb = b1v[wid * 128 + nt * 16 + l16];
        #pragma unroll
        for (int mt = 0; mt < 2; ++mt) {
            #pragma unroll
            for (int r = 0; r < 4; ++r) {
                float v = fmaxf(C1[mt][nt][r] + bb, 0.f);
                h1s[(mt * 16 + quad * 4 + r) * 520 + wid * 128 + nt * 16 + l16] = f2b(v);
            }
        }
    }
    __syncthreads();

    // ---- phase 2: h2 = h1(32 x 512) @ W2, single pass, wave owns 64 N-cols ------------
    floatx4 C2[2][4];
    #pragma unroll
    for (int mt = 0; mt < 2; ++mt)
        #pragma unroll
        for (int nt = 0; nt < 4; ++nt)
            C2[mt][nt] = (floatx4){0.f, 0.f, 0.f, 0.f};

    #pragma unroll 4
    for (int kk = 0; kk < 16; ++kk) {
        short8 a0 = ld8s(&h1s[(l16) * 520 + kk * 32 + quad * 8]);
        short8 a1 = ld8s(&h1s[(16 + l16) * 520 + kk * 32 + quad * 8]);
        #pragma unroll
        for (int nt = 0; nt < 4; ++nt) {
            short8 b = ld8s(w2p + (((wid * 4 + nt) * 16 + kk) * 64 + lane) * 8);
            C2[0][nt] = __builtin_amdgcn_mfma_f32_16x16x32_bf16(a0, b, C2[0][nt], 0, 0, 0);
            C2[1][nt] = __builtin_amdgcn_mfma_f32_16x16x32_bf16(a1, b, C2[1][nt], 0, 0, 0);
        }
    }
    __syncthreads();    // h1 reads complete -> safe to alias h2s onto h1s

    #pragma unroll
    for (int nt = 0; nt < 4; ++nt) {
        float bb = b2v[wid * 64 + nt * 16 + l16];
        #pragma unroll
        for (int mt = 0; mt < 2; ++mt)
            #pragma unroll
            for (int r = 0; r < 4; ++r)
                h2s[(mt * 16 + quad * 4 + r) * 264 + wid * 64 + nt * 16 + l16] =
                    f2b(fmaxf(C2[mt][nt][r] + bb, 0.f));
    }
    __syncthreads();

    // ---- phase 3: dnn = relu(h2 . W3 + b3); out = sigmoid(att + dnn), f32 -------------
    {
        int s = tid >> 3, part = tid & 7;     // 8 lanes per sample, 32 elems each
        float acc = 0.f;
        #pragma unroll 8
        for (int j = 0; j < 32; ++j) {
            int jj = part * 32 + j;
            acc += b2f(h2s[s * 264 + jj]) * w3v[jj];
        }
        acc += __shfl_xor(acc, 1, 64);
        acc += __shfl_xor(acc, 2, 64);
        acc += __shfl_xor(acc, 4, 64);
        if (part == 0) {
            float dnn = fmaxf(acc + b3v[0], 0.f);
            float v = dnn + att_in[S0 + s];
            out[S0 + s] = 1.f / (1.f + __expf(-v));
        }
    }
}

extern "C" void kernel_launch(void* const* d_in, const int* in_sizes, int n_in,
                              void* d_out, int out_size, void* d_ws, size_t ws_size,
                              hipStream_t stream)
{
    (void)in_sizes; (void)n_in; (void)out_size; (void)ws_size;

    const int*   X    = (const int*)d_in[0];
    const float* emb  = (const float*)d_in[1];
    const float* WQ   = (const float*)d_in[2];
    const float* WK   = (const float*)d_in[3];
    const float* WV   = (const float*)d_in[4];
    const float* WR   = (const float*)d_in[5];
    const float* W1   = (const float*)d_in[6];
    const float* b1   = (const float*)d_in[7];
    const float* W2   = (const float*)d_in[8];
    const float* b2   = (const float*)d_in[9];
    const float* W3   = (const float*)d_in[10];
    const float* b3   = (const float*)d_in[11];
    const float* Wlin = (const float*)d_in[12];

    char* ws = (char*)d_ws;
    float*          att_logit = (float*)ws;                          // 16384 f32 = 64KB
    unsigned short* wqt = (unsigned short*)(ws + 65536);             // 3*4096 shorts each
    unsigned short* wkt = wqt + 3 * 4096;
    unsigned short* wvt = wkt + 3 * 4096;
    unsigned short* wrt = wvt + 3 * 4096;
    unsigned short* w1p = wrt + 3 * 4096;                            // 2496*512 shorts
    unsigned short* w2p = w1p + 2496 * 512;                          // 256*512 shorts

    prep_all<<<880, 256, 0, stream>>>(WQ, WK, WV, WR, W1, W2,
                                      wqt, wkt, wvt, wrt, w1p, w2p);
    attn_kernel<<<8192, 128, 0, stream>>>(X, emb, wqt, wkt, wvt, wrt, Wlin, att_logit);
    dnn_kernel<<<512, 256, 0, stream>>>(X, emb, w1p, b1, w2p, b2, W3, b3, att_logit,
                                        (float*)d_out);
}